// Round 3
// baseline (2356.171 us; speedup 1.0000x reference)
//
#include <hip/hip_runtime.h>

#define B_ 64
#define L_ 2048
#define D_ 128
#define LP 2056   // padded rows per batch (3 left, 5 right incl. alignment)
#define PAD 3     // SAME-pad left for W=8

typedef __attribute__((ext_vector_type(8))) short short8;
typedef __attribute__((ext_vector_type(4))) float f32x4;
typedef __attribute__((ext_vector_type(4))) unsigned short us4;

static __device__ __forceinline__ float bf2f(unsigned short u) {
  return __uint_as_float(((unsigned int)u) << 16);
}
static __device__ __forceinline__ unsigned short f2bf(float f) {
  unsigned int x = __float_as_uint(f);
  unsigned int r = (x + 0x7fffu + ((x >> 16) & 1u)) >> 16;  // RNE
  return (unsigned short)r;
}

// ---------------------------------------------------------------------------
// K0: gather tok -> bf16 padded [B,LP,128]; gather bias; transpose weights.
// ---------------------------------------------------------------------------
__global__ __launch_bounds__(256) void k_prep(
    const int* __restrict__ code, const float* __restrict__ E,
    const float* __restrict__ bias_table, const float* __restrict__ Wx,
    const float* __restrict__ c1w, const float* __restrict__ c2w,
    unsigned short* __restrict__ tokpad,
    unsigned short* __restrict__ WxT, unsigned short* __restrict__ c1wT,
    unsigned short* __restrict__ c2wT, float* __restrict__ biasg)
{
  int id = blockIdx.x * 256 + threadIdx.x;
  const int N0 = B_ * LP * 16;            // tokpad in uint4 (8 bf16) chunks
  if (id < N0) {
    int b = id / (LP * 16); int rem = id % (LP * 16);
    int row = rem >> 4, c8 = rem & 15;
    uint4 o = {0u,0u,0u,0u};
    if (row >= PAD && row < PAD + L_) {
      int cd = code[b * L_ + (row - PAD)];
      const float4* e = (const float4*)(E + (size_t)cd * D_ + c8 * 8);
      float4 e0 = e[0], e1 = e[1];
      o.x = f2bf(e0.x) | ((unsigned int)f2bf(e0.y) << 16);
      o.y = f2bf(e0.z) | ((unsigned int)f2bf(e0.w) << 16);
      o.z = f2bf(e1.x) | ((unsigned int)f2bf(e1.y) << 16);
      o.w = f2bf(e1.z) | ((unsigned int)f2bf(e1.w) << 16);
    }
    ((uint4*)tokpad)[id] = o;
    return;
  }
  id -= N0;
  const int N2 = B_ * L_;
  if (id < N2) { biasg[id] = bias_table[code[id]]; return; }
  id -= N2;
  const int N3 = 192 * 128;               // WxT[c][d]
  if (id < N3) { int c = id >> 7, d = id & 127; WxT[id] = f2bf(Wx[d * 192 + c]); return; }
  id -= N3;
  const int N4 = 8 * 64 * 128;            // c1wT[w][c][d]
  if (id < N4) {
    int w = id >> 13, c = (id >> 7) & 63, d = id & 127;
    c1wT[id] = f2bf(c1w[(w * 128 + d) * 64 + c]); return;
  }
  id -= N4;
  const int N5 = 8 * 64 * 64;             // c2wT[w][c][d]
  if (id < N5) {
    int w = id >> 12, c = (id >> 6) & 63, d = id & 63;
    c2wT[id] = f2bf(c2w[(w * 64 + d) * 64 + c]);
  }
}

// ---------------------------------------------------------------------------
// K1: x_proj = tok @ Wx + b_gru[0] -> bf16 TRANSPOSED [B,192,L].
// R10: C tiles bounce through LDS (reusing Bt, same 192x136 shape) so the
// global store is 256 B-contiguous per row.
// ---------------------------------------------------------------------------
__global__ __launch_bounds__(256) void k_xproj(
    const unsigned short* __restrict__ tokpad, const unsigned short* __restrict__ WxT,
    const float* __restrict__ bg, unsigned short* __restrict__ xprojT)
{
  __shared__ __align__(16) unsigned short At[128 * 136];
  __shared__ __align__(16) unsigned short Bt[192 * 136];
  int b = blockIdx.x >> 4;
  int l0 = (blockIdx.x & 15) << 7;
  int tid = threadIdx.x;
  for (int i = tid; i < 128 * 16; i += 256) {
    int row = i >> 4, c8 = i & 15;
    uint4 v = ((const uint4*)tokpad)[(b * LP + PAD + l0 + row) * 16 + c8];
    *((uint4*)&At[row * 136 + c8 * 8]) = v;
  }
  for (int i = tid; i < 192 * 16; i += 256) {
    int row = i >> 4, c8 = i & 15;
    uint4 v = ((const uint4*)WxT)[i];
    *((uint4*)&Bt[row * 136 + c8 * 8]) = v;
  }
  __syncthreads();
  int wave = tid >> 6, lane = tid & 63;
  int m = lane & 15, q = lane >> 4;
  f32x4 acc[2][12];
  #pragma unroll
  for (int mt = 0; mt < 2; ++mt)
    #pragma unroll
    for (int nt = 0; nt < 12; ++nt) acc[mt][nt] = (f32x4){0.f,0.f,0.f,0.f};
  #pragma unroll
  for (int ks = 0; ks < 4; ++ks) {
    int kof = ks * 32 + q * 8;
    short8 a[2], bb[12];
    #pragma unroll
    for (int mt = 0; mt < 2; ++mt)
      a[mt] = *(const short8*)&At[(wave * 32 + mt * 16 + m) * 136 + kof];
    #pragma unroll
    for (int nt = 0; nt < 12; ++nt)
      bb[nt] = *(const short8*)&Bt[(nt * 16 + m) * 136 + kof];
    #pragma unroll
    for (int mt = 0; mt < 2; ++mt)
      #pragma unroll
      for (int nt = 0; nt < 12; ++nt)
        acc[mt][nt] = __builtin_amdgcn_mfma_f32_16x16x32_bf16(a[mt], bb[nt], acc[mt][nt], 0, 0, 0);
  }
  __syncthreads();                        // all MFMA reads of Bt done
  // deposit C (+bias, bf16) transposed into Bt[c][l]  (l = 0..127)
  #pragma unroll
  for (int mt = 0; mt < 2; ++mt) {
    int lrow = wave * 32 + mt * 16 + q * 4;
    #pragma unroll
    for (int nt = 0; nt < 12; ++nt) {
      int c = nt * 16 + m;                 // C col = lane&15
      float b0 = bg[c];
      us4 val;
      val.x = f2bf(acc[mt][nt][0] + b0);
      val.y = f2bf(acc[mt][nt][1] + b0);
      val.z = f2bf(acc[mt][nt][2] + b0);
      val.w = f2bf(acc[mt][nt][3] + b0);
      *((us4*)&Bt[c * 136 + lrow]) = val;
    }
  }
  __syncthreads();
  // coalesced write-out: 16 lanes x 16 B = 256 B contiguous per c-row
  for (int i = tid; i < 192 * 16; i += 256) {
    int row = i >> 4, c8 = i & 15;
    uint4 v = *((const uint4*)&Bt[row * 136 + c8 * 8]);
    ((uint4*)&xprojT[((size_t)b * 192 + row) * L_ + l0])[c8] = v;
  }
}

// ---------------------------------------------------------------------------
// K2 (fused): blocks 0..63 = GRU scan; blocks 64..255 = conv1+conv2 with
// halo recompute (l1 LDS-only, identical bf16 rounding). No cross-block deps.
//
// R13 GRU: ONE wave computes ALL THREE gates (lane j owns Wh columns j,
// 64+j, 128+j => 192 f32 weights in VGPRs, legal at waves_per_eu(1,1)).
// z[j], r[j], s_h[j] are now lane-local => h_new[j] computed with ZERO
// cross-wave communication: no barrier, and exactly ONE LDS round trip per
// step (write h[j] -> lgkmcnt0 -> 16 broadcast ds_read_b128). R10/R12 had
// TWO round trips + 48 broadcast reads/step on the shared LDS pipe; that
// structure, not the barrier count, was the ~1200 cyc/step floor.
// Numerics bitwise-identical: same per-column fma order (bias in a0,
// chunks 0..15, (a0+a1)+(a2+a3)), same x rows, same gate formulas — z/r/s
// previously passed through LDS as exact f32 bits, now stay in-lane.
// ---------------------------------------------------------------------------
#define LGKM0()   asm volatile("s_waitcnt lgkmcnt(0)" ::: "memory")

__global__ __launch_bounds__(192)
__attribute__((amdgpu_waves_per_eu(1, 1)))
void k_fused(
    const unsigned short* __restrict__ xprojT, const float* __restrict__ Wh,
    const float* __restrict__ bg, float* __restrict__ h_t,
    const unsigned short* __restrict__ tokpad,
    const unsigned short* __restrict__ c1wT, const float* __restrict__ c1b,
    const unsigned short* __restrict__ c2wT, const float* __restrict__ c2b,
    unsigned short* __restrict__ c2o)
{
  __shared__ __align__(16) unsigned short pool[39744];
  int bid = blockIdx.x;
  int tid = threadIdx.x;

  if (bid < 64) {
    // ================= GRU scan (R13: 1 wave, all gates lane-local) ======
    if (tid >= 64) return;                // single-wave scan
    float* hb = (float*)pool;             // 64-float h buffer (own wave only)
    int b = bid;
    int j = tid;                          // hidden index 0..63

    // Weights: lane j holds Wh[:, j] (z), Wh[:, 64+j] (r), Wh[:, 128+j] (h)
#define DECL_W3(i) \
    float4 wz##i = {Wh[(4*i+0)*192+j],     Wh[(4*i+1)*192+j],     Wh[(4*i+2)*192+j],     Wh[(4*i+3)*192+j]}; \
    float4 wr##i = {Wh[(4*i+0)*192+64+j],  Wh[(4*i+1)*192+64+j],  Wh[(4*i+2)*192+64+j],  Wh[(4*i+3)*192+64+j]}; \
    float4 wh##i = {Wh[(4*i+0)*192+128+j], Wh[(4*i+1)*192+128+j], Wh[(4*i+2)*192+128+j], Wh[(4*i+3)*192+128+j]};
    DECL_W3(0)  DECL_W3(1)  DECL_W3(2)  DECL_W3(3)
    DECL_W3(4)  DECL_W3(5)  DECL_W3(6)  DECL_W3(7)
    DECL_W3(8)  DECL_W3(9)  DECL_W3(10) DECL_W3(11)
    DECL_W3(12) DECL_W3(13) DECL_W3(14) DECL_W3(15)
#undef DECL_W3
#define OPAQ1(V) asm volatile("" : "+v"(V.x), "+v"(V.y), "+v"(V.z), "+v"(V.w));
#define OPAQ3(i) OPAQ1(wz##i) OPAQ1(wr##i) OPAQ1(wh##i)
    OPAQ3(0)  OPAQ3(1)  OPAQ3(2)  OPAQ3(3)
    OPAQ3(4)  OPAQ3(5)  OPAQ3(6)  OPAQ3(7)
    OPAQ3(8)  OPAQ3(9)  OPAQ3(10) OPAQ3(11)
    OPAQ3(12) OPAQ3(13) OPAQ3(14) OPAQ3(15)
#undef OPAQ3
#undef OPAQ1
    float biasz = bg[192 + j];
    float biasr = bg[192 + 64 + j];
    float biash = bg[192 + 128 + j];
    float hreg = 0.f;
    hb[j] = 0.f;
    LGKM0();

    const unsigned short* xz = xprojT + ((size_t)b * 192 + j) * L_;
    const unsigned short* xr = xz + (size_t)64 * L_;
    const unsigned short* xh = xz + (size_t)128 * L_;
    const float4* hl4 = (const float4*)hb;

    uint4 cz0 = ((const uint4*)xz)[0], cz1 = ((const uint4*)xz)[1];
    uint4 cr0 = ((const uint4*)xr)[0], cr1 = ((const uint4*)xr)[1];
    uint4 ch0 = ((const uint4*)xh)[0], ch1 = ((const uint4*)xh)[1];

#define MCH(i) \
    h4 = hl4[i]; \
    az0 = fmaf(h4.x, wz##i.x, az0); az1 = fmaf(h4.y, wz##i.y, az1); az2 = fmaf(h4.z, wz##i.z, az2); az3 = fmaf(h4.w, wz##i.w, az3); \
    ar0 = fmaf(h4.x, wr##i.x, ar0); ar1 = fmaf(h4.y, wr##i.y, ar1); ar2 = fmaf(h4.z, wr##i.z, ar2); ar3 = fmaf(h4.w, wr##i.w, ar3); \
    ah0 = fmaf(h4.x, wh##i.x, ah0); ah1 = fmaf(h4.y, wh##i.y, ah1); ah2 = fmaf(h4.z, wh##i.z, ah2); ah3 = fmaf(h4.w, wh##i.w, ah3);

#define STEP(XZ, XR, XH) { \
    float az0 = biasz, az1 = 0.f, az2 = 0.f, az3 = 0.f; \
    float ar0 = biasr, ar1 = 0.f, ar2 = 0.f, ar3 = 0.f; \
    float ah0 = biash, ah1 = 0.f, ah2 = 0.f, ah3 = 0.f; \
    { float4 h4; \
      MCH(0)  MCH(1)  MCH(2)  MCH(3) \
      MCH(4)  MCH(5)  MCH(6)  MCH(7) \
      MCH(8)  MCH(9)  MCH(10) MCH(11) \
      MCH(12) MCH(13) MCH(14) MCH(15) } \
    float sz = (az0 + az1) + (az2 + az3); \
    float sr = (ar0 + ar1) + (ar2 + ar3); \
    float sh = (ah0 + ah1) + (ah2 + ah3); \
    float xvz = bf2f((unsigned short)(XZ)); \
    float xvr = bf2f((unsigned short)(XR)); \
    float xvh = bf2f((unsigned short)(XH)); \
    float zg = 1.f / (1.f + __expf(-(xvz + sz))); \
    float rg = 1.f / (1.f + __expf(-(xvr + sr))); \
    float e2 = __expf(-2.f * (xvh + rg * sh)); \
    float hh = fmaf(2.f, __frcp_rn(1.f + e2), -1.f); \
    hreg = zg * hreg + (1.f - zg) * hh; \
    hb[j] = hreg; \
    LGKM0(); \
  }

#define STEP8(CZ, CR, CHX) \
    STEP(CZ.x & 0xffffu, CR.x & 0xffffu, CHX.x & 0xffffu) \
    STEP(CZ.x >> 16,     CR.x >> 16,     CHX.x >> 16) \
    STEP(CZ.y & 0xffffu, CR.y & 0xffffu, CHX.y & 0xffffu) \
    STEP(CZ.y >> 16,     CR.y >> 16,     CHX.y >> 16) \
    STEP(CZ.z & 0xffffu, CR.z & 0xffffu, CHX.z & 0xffffu) \
    STEP(CZ.z >> 16,     CR.z >> 16,     CHX.z >> 16) \
    STEP(CZ.w & 0xffffu, CR.w & 0xffffu, CHX.w & 0xffffu) \
    STEP(CZ.w >> 16,     CR.w >> 16,     CHX.w >> 16)

    for (int t0 = 0; t0 < L_; t0 += 16) {
      int tn = (t0 + 16 < L_) ? t0 + 16 : t0;
      uint4 nz0 = ((const uint4*)(xz + tn))[0], nz1 = ((const uint4*)(xz + tn))[1];
      uint4 nr0 = ((const uint4*)(xr + tn))[0], nr1 = ((const uint4*)(xr + tn))[1];
      uint4 nh0 = ((const uint4*)(xh + tn))[0], nh1 = ((const uint4*)(xh + tn))[1];
      STEP8(cz0, cr0, ch0)
      STEP8(cz1, cr1, ch1)
      cz0 = nz0; cz1 = nz1;
      cr0 = nr0; cr1 = nr1;
      ch0 = nh0; ch1 = nh1;
    }
#undef STEP8
#undef STEP
#undef MCH
    h_t[b * 64 + j] = hreg;
    return;
  }

  // ================= fused conv1+conv2 (halo recompute) =================
  unsigned short* At    = pool;           // 152 x 136 shorts = 41344 B
  unsigned short* l1buf = pool + 20672;   // 144 x 72  shorts = 20736 B
  unsigned short* Bw    = pool + 31040;   //  64 x 136 shorts = 17408 B
  int wv = tid >> 6, lane = tid & 63;
  int m = lane & 15, q = lane >> 4;

  for (int job = bid - 64; job < 1024; job += 192) {
    int b = job >> 4;
    int l0 = (job & 15) << 7;
    __syncthreads();                      // prev job fully consumed
    for (int i = tid; i < 152 * 16; i += 192) {
      int row = i >> 4, c8 = i & 15;
      int p = l0 - 3 + row;
      p = p < 0 ? 0 : (p > 2055 ? 2055 : p);
      *((uint4*)&At[row * 136 + c8 * 8]) = ((const uint4*)tokpad)[(b * LP + p) * 16 + c8];
    }
    // ---- conv1: l1 rows [l0-3, l0+140] (9 M-tiles of 16), K=128 ----
    f32x4 acc[3][4];
    #pragma unroll
    for (int mt = 0; mt < 3; ++mt)
      #pragma unroll
      for (int nt = 0; nt < 4; ++nt) acc[mt][nt] = (f32x4){0.f,0.f,0.f,0.f};
    for (int w8 = 0; w8 < 8; ++w8) {
      __syncthreads();
      for (int i = tid; i < 64 * 16; i += 192) {
        int row = i >> 4, c8 = i & 15;
        *((uint4*)&Bw[row * 136 + c8 * 8]) = ((const uint4*)c1wT)[(w8 * 64 + row) * 16 + c8];
      }
      __syncthreads();
      #pragma unroll
      for (int ks = 0; ks < 4; ++ks) {
        int kof = ks * 32 + q * 8;
        short8 a[3], bb[4];
        #pragma unroll
        for (int mt = 0; mt < 3; ++mt) {
          int tl = wv + 3 * mt;
          a[mt] = *(const short8*)&At[(tl * 16 + m + w8) * 136 + kof];
        }
        #pragma unroll
        for (int nt = 0; nt < 4; ++nt)
          bb[nt] = *(const short8*)&Bw[(nt * 16 + m) * 136 + kof];
        #pragma unroll
        for (int mt = 0; mt < 3; ++mt)
          #pragma unroll
          for (int nt = 0; nt < 4; ++nt)
            acc[mt][nt] = __builtin_amdgcn_mfma_f32_16x16x32_bf16(a[mt], bb[nt], acc[mt][nt], 0, 0, 0);
      }
    }
    #pragma unroll
    for (int mt = 0; mt < 3; ++mt) {
      int tl = wv + 3 * mt;
      #pragma unroll
      for (int nt = 0; nt < 4; ++nt) {
        int c = nt * 16 + m;
        float bs = c1b[c];
        #pragma unroll
        for (int r = 0; r < 4; ++r) {
          float v = fmaxf(acc[mt][nt][r] + bs, 0.f);
          l1buf[(tl * 16 + q * 4 + r) * 72 + c] = f2bf(v);
        }
      }
    }
    __syncthreads();
    for (int i2 = tid; i2 < 135 * 8; i2 += 192) {
      int i = i2 >> 3, c8 = i2 & 7;
      int jrow = l0 - 3 + i;
      if (jrow < 0 || jrow > 2047) {
        uint4 z4 = {0u,0u,0u,0u};
        *((uint4*)&l1buf[i * 72 + c8 * 8]) = z4;
      }
    }
    // ---- conv2: out rows [l0, l0+127] (8 M-tiles), K=64 ----
    f32x4 acc2[3][4];
    #pragma unroll
    for (int mt = 0; mt < 3; ++mt)
      #pragma unroll
      for (int nt = 0; nt < 4; ++nt) acc2[mt][nt] = (f32x4){0.f,0.f,0.f,0.f};
    for (int w8 = 0; w8 < 8; ++w8) {
      __syncthreads();
      for (int i = tid; i < 64 * 8; i += 192) {
        int row = i >> 3, c8 = i & 7;
        *((uint4*)&Bw[row * 72 + c8 * 8]) = ((const uint4*)c2wT)[(w8 * 64 + row) * 8 + c8];
      }
      __syncthreads();
      #pragma unroll
      for (int ks = 0; ks < 2; ++ks) {
        int kof = ks * 32 + q * 8;
        short8 a[3], bb[4];
        #pragma unroll
        for (int mt = 0; mt < 3; ++mt) {
          int tl = wv + 3 * mt;
          if (tl < 8)
            a[mt] = *(const short8*)&l1buf[(tl * 16 + m + w8) * 72 + kof];
        }
        #pragma unroll
        for (int nt = 0; nt < 4; ++nt)
          bb[nt] = *(const short8*)&Bw[(nt * 16 + m) * 72 + kof];
        #pragma unroll
        for (int mt = 0; mt < 3; ++mt) {
          int tl = wv + 3 * mt;
          if (tl < 8)
            #pragma unroll
            for (int nt = 0; nt < 4; ++nt)
              acc2[mt][nt] = __builtin_amdgcn_mfma_f32_16x16x32_bf16(a[mt], bb[nt], acc2[mt][nt], 0, 0, 0);
        }
      }
    }
    #pragma unroll
    for (int mt = 0; mt < 3; ++mt) {
      int tl = wv + 3 * mt;
      if (tl < 8) {
        #pragma unroll
        for (int nt = 0; nt < 4; ++nt) {
          int c = nt * 16 + m;
          float bs = c2b[c];
          #pragma unroll
          for (int r = 0; r < 4; ++r)
            c2o[(size_t)(b * L_ + l0 + tl * 16 + q * 4 + r) * 64 + c] = f2bf(acc2[mt][nt][r] + bs);
        }
      }
    }
  }
}

// ---------------------------------------------------------------------------
// K5: per-batch tail: L2=c2o*h_t -> l2norm -> conv3 -> softmax alpha ->
//     n_hat = sum alpha*tok -> logits = tok.n_hat + bias -> softmax -> out
// ---------------------------------------------------------------------------
__global__ __launch_bounds__(256) void k_final(
    const unsigned short* __restrict__ tokpad, const unsigned short* __restrict__ c2o,
    const float* __restrict__ h_t, const float* __restrict__ c3w,
    const float* __restrict__ c3b, const float* __restrict__ biasg,
    float* __restrict__ out)
{
  __shared__ float Lf[71 * 65];
  __shared__ float a_lds[2048];
  __shared__ float l_lds[2048];
  __shared__ float red[256];
  __shared__ float nred[512];
  __shared__ float nhat[128];
  __shared__ float ht[64];
  __shared__ float c3[512];
  int b = blockIdx.x, tid = threadIdx.x, lane = tid & 63, wave = tid >> 6;
  if (tid < 64) ht[tid] = h_t[b * 64 + tid];
  for (int i = tid; i < 512; i += 256) c3[i] = c3w[i];
  float c3bias = c3b[0];
  __syncthreads();
  // ---- pass 1: a_logits via normalized features + conv3 (tiles of 64 l) ----
  for (int tile = 0; tile < 32; ++tile) {
    int lt = tile << 6;
    for (int i0 = wave; i0 < 71; i0 += 4) {
      int l = lt - 3 + i0;
      float v = 0.f;
      if (l >= 0 && l < L_) v = bf2f(c2o[((size_t)b * L_ + l) * 64 + lane]) * ht[lane];
      float ss = v * v;
      #pragma unroll
      for (int msk = 1; msk < 64; msk <<= 1) ss += __shfl_xor(ss, msk);
      Lf[i0 * 65 + lane] = v * rsqrtf(ss + 1e-12f);
    }
    __syncthreads();
    {
      int u = lane, part = wave;
      float p = 0.f;
      #pragma unroll
      for (int w = 0; w < 8; ++w)
        #pragma unroll
        for (int cc = 0; cc < 16; ++cc) {
          int c = part * 16 + cc;
          p += Lf[(u + w) * 65 + c] * c3[w * 64 + c];
        }
      red[tid] = p;
    }
    __syncthreads();
    if (tid < 64) a_lds[lt + tid] = red[tid] + red[64 + tid] + red[128 + tid] + red[192 + tid] + c3bias;
    __syncthreads();
  }
  // ---- pass 2: softmax alpha over 2048 ----
  {
    float mx = -1e30f;
    for (int i = tid; i < 2048; i += 256) mx = fmaxf(mx, a_lds[i]);
    #pragma unroll
    for (int msk = 1; msk < 64; msk <<= 1) mx = fmaxf(mx, __shfl_xor(mx, msk));
    if (lane == 0) red[wave] = mx;
    __syncthreads();
    mx = fmaxf(fmaxf(red[0], red[1]), fmaxf(red[2], red[3]));
    float sm = 0.f;
    for (int i = tid; i < 2048; i += 256) sm += __expf(a_lds[i] - mx);
    #pragma unroll
    for (int msk = 1; msk < 64; msk <<= 1) sm += __shfl_xor(sm, msk);
    __syncthreads();
    if (lane == 0) red[wave] = sm;
    __syncthreads();
    sm = red[0] + red[1] + red[2] + red[3];
    float inv = 1.f / sm;
    for (int i = tid; i < 2048; i += 256) a_lds[i] = __expf(a_lds[i] - mx) * inv;
    __syncthreads();
  }
  // ---- pass 3: n_hat[128] = sum_l alpha_l * tok[l][:] ----
  {
    int d2 = tid & 63, g = tid >> 6;
    float ax = 0.f, ay = 0.f;
    for (int l = g; l < L_; l += 4) {
      unsigned int uu = *(const unsigned int*)&tokpad[((size_t)b * LP + PAD + l) * 128 + d2 * 2];
      float al = a_lds[l];
      ax += al * bf2f((unsigned short)(uu & 0xffffu));
      ay += al * bf2f((unsigned short)(uu >> 16));
    }
    nred[g * 128 + d2 * 2] = ax;
    nred[g * 128 + d2 * 2 + 1] = ay;
    __syncthreads();
    if (tid < 128) nhat[tid] = nred[tid] + nred[128 + tid] + nred[256 + tid] + nred[384 + tid];
    __syncthreads();
  }
  // ---- pass 4: logits = tok . n_hat + bias ----
  for (int li = 0; li < 8; ++li) {
    int l = li * 256 + tid;
    const uint4* rowp = (const uint4*)&tokpad[((size_t)b * LP + PAD + l) * 128];
    float s = 0.f;
    #pragma unroll
    for (int jj = 0; jj < 16; ++jj) {
      uint4 uu = rowp[jj];
      s += bf2f((unsigned short)(uu.x & 0xffffu)) * nhat[jj*8+0]
         + bf2f((unsigned short)(uu.x >> 16))     * nhat[jj*8+1]
         + bf2f((unsigned short)(uu.y & 0xffffu)) * nhat[jj*8+2]
         + bf2f((unsigned short)(uu.y >> 16))     * nhat[jj*8+3]
         + bf2f((unsigned short)(uu.z & 0xffffu)) * nhat[jj*8+4]
         + bf2f((unsigned short)(uu.z >> 16))     * nhat[jj*8+5]
         + bf2f((unsigned short)(uu.w & 0xffffu)) * nhat[jj*8+6]
         + bf2f((unsigned short)(uu.w >> 16))     * nhat[jj*8+7];
    }
    l_lds[l] = s + biasg[b * L_ + l];
  }
  __syncthreads();
  // ---- pass 5: final softmax -> out ----
  {
    float mx = -1e30f;
    for (int i = tid; i < 2048; i += 256) mx = fmaxf(mx, l_lds[i]);
    #pragma unroll
    for (int msk = 1; msk < 64; msk <<= 1) mx = fmaxf(mx, __shfl_xor(mx, msk));
    __syncthreads();
    if (lane == 0) red[wave] = mx;
    __syncthreads();
    mx = fmaxf(fmaxf(red[0], red[1]), fmaxf(red[2], red[3]));
    float sm = 0.f;
    for (int i = tid; i < 2048; i += 256) sm += __expf(l_lds[i] - mx);
    #pragma unroll
    for (int msk = 1; msk < 64; msk <<= 1) sm += __shfl_xor(sm, msk);
    __syncthreads();
    if (lane == 0) red[wave] = sm;
    __syncthreads();
    sm = red[0] + red[1] + red[2] + red[3];
    float inv = 1.f / sm;
    for (int i = tid; i < 2048; i += 256) out[b * L_ + i] = __expf(l_lds[i] - mx) * inv;
  }
}

// ---------------------------------------------------------------------------
extern "C" void kernel_launch(void* const* d_in, const int* in_sizes, int n_in,
                              void* d_out, int out_size, void* d_ws, size_t ws_size,
                              hipStream_t stream) {
  const int*   code = (const int*)d_in[0];
  const float* E    = (const float*)d_in[1];
  const float* bt   = (const float*)d_in[2];
  const float* Wx   = (const float*)d_in[3];
  const float* Wh   = (const float*)d_in[4];
  const float* bg   = (const float*)d_in[5];
  const float* c1w  = (const float*)d_in[6];
  const float* c1b  = (const float*)d_in[7];
  const float* c2w  = (const float*)d_in[8];
  const float* c2b  = (const float*)d_in[9];
  const float* c3w  = (const float*)d_in[10];
  const float* c3b  = (const float*)d_in[11];
  char* ws = (char*)d_ws;
  unsigned short* tokpad = (unsigned short*)(ws);               // 33,685,504 B
  unsigned short* xprojT = (unsigned short*)(ws + 50528256);    // 50,331,648 B
  unsigned short* c2o    = (unsigned short*)(ws + 100859904);   // 16,777,216 B
  unsigned short* WxT    = (unsigned short*)(ws + 117637120);   //     49,152 B
  unsigned short* c1wT   = (unsigned short*)(ws + 117686272);   //    131,072 B
  unsigned short* c2wT   = (unsigned short*)(ws + 117817344);   //     65,536 B
  float*          htp    = (float*)(ws + 117882880);            //     16,384 B
  float*          biasg  = (float*)(ws + 117899264);            //    524,288 B
  // total ws use: 118,423,552 B

  k_prep <<<9216, 256, 0, stream>>>(code, E, bt, Wx, c1w, c2w, tokpad, WxT, c1wT, c2wT, biasg);
  k_xproj<<<1024, 256, 0, stream>>>(tokpad, WxT, bg, xprojT);
  k_fused<<<256, 192, 0, stream>>>(xprojT, Wh, bg, htp, tokpad, c1wT, c1b, c2wT, c2b, c2o);
  k_final<<<64, 256, 0, stream>>>(tokpad, c2o, htp, c3w, c3b, biasg, (float*)d_out);
}

// Round 4
// 1769.601 us; speedup vs baseline: 1.3315x; 1.3315x over previous
//
#include <hip/hip_runtime.h>

#define B_ 64
#define L_ 2048
#define D_ 128
#define LP 2056   // padded rows per batch (3 left, 5 right incl. alignment)
#define PAD 3     // SAME-pad left for W=8

typedef __attribute__((ext_vector_type(8))) short short8;
typedef __attribute__((ext_vector_type(4))) float f32x4;
typedef __attribute__((ext_vector_type(4))) unsigned short us4;

static __device__ __forceinline__ float bf2f(unsigned short u) {
  return __uint_as_float(((unsigned int)u) << 16);
}
static __device__ __forceinline__ unsigned short f2bf(float f) {
  unsigned int x = __float_as_uint(f);
  unsigned int r = (x + 0x7fffu + ((x >> 16) & 1u)) >> 16;  // RNE
  return (unsigned short)r;
}

// ---------------------------------------------------------------------------
// K0: gather tok -> bf16 padded [B,LP,128]; gather bias; transpose weights.
// ---------------------------------------------------------------------------
__global__ __launch_bounds__(256) void k_prep(
    const int* __restrict__ code, const float* __restrict__ E,
    const float* __restrict__ bias_table, const float* __restrict__ Wx,
    const float* __restrict__ c1w, const float* __restrict__ c2w,
    unsigned short* __restrict__ tokpad,
    unsigned short* __restrict__ WxT, unsigned short* __restrict__ c1wT,
    unsigned short* __restrict__ c2wT, float* __restrict__ biasg)
{
  int id = blockIdx.x * 256 + threadIdx.x;
  const int N0 = B_ * LP * 16;            // tokpad in uint4 (8 bf16) chunks
  if (id < N0) {
    int b = id / (LP * 16); int rem = id % (LP * 16);
    int row = rem >> 4, c8 = rem & 15;
    uint4 o = {0u,0u,0u,0u};
    if (row >= PAD && row < PAD + L_) {
      int cd = code[b * L_ + (row - PAD)];
      const float4* e = (const float4*)(E + (size_t)cd * D_ + c8 * 8);
      float4 e0 = e[0], e1 = e[1];
      o.x = f2bf(e0.x) | ((unsigned int)f2bf(e0.y) << 16);
      o.y = f2bf(e0.z) | ((unsigned int)f2bf(e0.w) << 16);
      o.z = f2bf(e1.x) | ((unsigned int)f2bf(e1.y) << 16);
      o.w = f2bf(e1.z) | ((unsigned int)f2bf(e1.w) << 16);
    }
    ((uint4*)tokpad)[id] = o;
    return;
  }
  id -= N0;
  const int N2 = B_ * L_;
  if (id < N2) { biasg[id] = bias_table[code[id]]; return; }
  id -= N2;
  const int N3 = 192 * 128;               // WxT[c][d]
  if (id < N3) { int c = id >> 7, d = id & 127; WxT[id] = f2bf(Wx[d * 192 + c]); return; }
  id -= N3;
  const int N4 = 8 * 64 * 128;            // c1wT[w][c][d]
  if (id < N4) {
    int w = id >> 13, c = (id >> 7) & 63, d = id & 127;
    c1wT[id] = f2bf(c1w[(w * 128 + d) * 64 + c]); return;
  }
  id -= N4;
  const int N5 = 8 * 64 * 64;             // c2wT[w][c][d]
  if (id < N5) {
    int w = id >> 12, c = (id >> 6) & 63, d = id & 63;
    c2wT[id] = f2bf(c2w[(w * 64 + d) * 64 + c]);
  }
}

// ---------------------------------------------------------------------------
// K1: x_proj = tok @ Wx + b_gru[0] -> bf16, GATE-INTERLEAVED per lane:
// xg[b][j][t][{z,r,h,0}] (8 B per step). R14: same C bits as before (same
// acc, same f2bf), only the placement changed so the GRU lane reads ONE
// stream (uint4 = 2 steps) instead of three 64*L-strided streams.
// ---------------------------------------------------------------------------
__global__ __launch_bounds__(256) void k_xproj(
    const unsigned short* __restrict__ tokpad, const unsigned short* __restrict__ WxT,
    const float* __restrict__ bg, unsigned short* __restrict__ xg)
{
  __shared__ __align__(16) unsigned short At[128 * 136];
  __shared__ __align__(16) unsigned short Bt[192 * 136];
  int b = blockIdx.x >> 4;
  int l0 = (blockIdx.x & 15) << 7;
  int tid = threadIdx.x;
  for (int i = tid; i < 128 * 16; i += 256) {
    int row = i >> 4, c8 = i & 15;
    uint4 v = ((const uint4*)tokpad)[(b * LP + PAD + l0 + row) * 16 + c8];
    *((uint4*)&At[row * 136 + c8 * 8]) = v;
  }
  for (int i = tid; i < 192 * 16; i += 256) {
    int row = i >> 4, c8 = i & 15;
    uint4 v = ((const uint4*)WxT)[i];
    *((uint4*)&Bt[row * 136 + c8 * 8]) = v;
  }
  __syncthreads();
  int wave = tid >> 6, lane = tid & 63;
  int m = lane & 15, q = lane >> 4;
  f32x4 acc[2][12];
  #pragma unroll
  for (int mt = 0; mt < 2; ++mt)
    #pragma unroll
    for (int nt = 0; nt < 12; ++nt) acc[mt][nt] = (f32x4){0.f,0.f,0.f,0.f};
  #pragma unroll
  for (int ks = 0; ks < 4; ++ks) {
    int kof = ks * 32 + q * 8;
    short8 a[2], bb[12];
    #pragma unroll
    for (int mt = 0; mt < 2; ++mt)
      a[mt] = *(const short8*)&At[(wave * 32 + mt * 16 + m) * 136 + kof];
    #pragma unroll
    for (int nt = 0; nt < 12; ++nt)
      bb[nt] = *(const short8*)&Bt[(nt * 16 + m) * 136 + kof];
    #pragma unroll
    for (int mt = 0; mt < 2; ++mt)
      #pragma unroll
      for (int nt = 0; nt < 12; ++nt)
        acc[mt][nt] = __builtin_amdgcn_mfma_f32_16x16x32_bf16(a[mt], bb[nt], acc[mt][nt], 0, 0, 0);
  }
  __syncthreads();                        // all MFMA reads of Bt done
  // deposit C (+bias, bf16) transposed into Bt[c][l]  (l = 0..127)
  #pragma unroll
  for (int mt = 0; mt < 2; ++mt) {
    int lrow = wave * 32 + mt * 16 + q * 4;
    #pragma unroll
    for (int nt = 0; nt < 12; ++nt) {
      int c = nt * 16 + m;                 // C col = lane&15
      float b0 = bg[c];
      us4 val;
      val.x = f2bf(acc[mt][nt][0] + b0);
      val.y = f2bf(acc[mt][nt][1] + b0);
      val.z = f2bf(acc[mt][nt][2] + b0);
      val.w = f2bf(acc[mt][nt][3] + b0);
      *((us4*)&Bt[c * 136 + lrow]) = val;
    }
  }
  __syncthreads();
  // gate-interleaved write-out: per (j, 4-step group): read z/r/h 4-wide,
  // pack [z|r<<16, h] per step, store 2 x uint4 (32 B contiguous per lane).
  for (int i = tid; i < 64 * 32; i += 256) {
    int j = i >> 5, g = i & 31;           // steps l = 4g..4g+3
    us4 z4 = *(const us4*)&Bt[j * 136 + g * 4];
    us4 r4 = *(const us4*)&Bt[(64 + j) * 136 + g * 4];
    us4 h4 = *(const us4*)&Bt[(128 + j) * 136 + g * 4];
    uint4 o0, o1;
    o0.x = (unsigned)z4.x | ((unsigned)r4.x << 16); o0.y = (unsigned)h4.x;
    o0.z = (unsigned)z4.y | ((unsigned)r4.y << 16); o0.w = (unsigned)h4.y;
    o1.x = (unsigned)z4.z | ((unsigned)r4.z << 16); o1.y = (unsigned)h4.z;
    o1.z = (unsigned)z4.w | ((unsigned)r4.w << 16); o1.w = (unsigned)h4.w;
    size_t stp = (size_t)(b * 64 + j) * L_ + l0 + g * 4;  // step index
    ((uint4*)xg)[stp >> 1]       = o0;
    ((uint4*)xg)[(stp >> 1) + 1] = o1;
  }
}

// ---------------------------------------------------------------------------
// K2 (fused): blocks 0..63 = GRU scan; blocks 64..255 = conv1+conv2 with
// halo recompute (l1 LDS-only, identical bf16 rounding). No cross-block deps.
//
// R14 GRU: R13's 1-wave all-gates design (lane j owns Wh cols j, 64+j,
// 128+j; zero barriers; one LDS round trip/step: write h[j] -> lgkmcnt0 ->
// 16 broadcast ds_read_b128), with the register deficit fixed. R13 spilled
// (VGPR_Count=256 + scratch traffic) because THREE x-streams needed 48
// prefetch VGPRs. R14 reads the gate-interleaved xg stream: cur+nxt uint4
// = 12 regs. Demand ~240 < 256.
// Numerics bitwise-identical to R10/R12: same per-column fma order (bias in
// a0, chunks 0..15, (a0+a1)+(a2+a3)), same gate formulas; z/r/s stay
// in-lane; h passes through LDS as exact f32 bits.
// ---------------------------------------------------------------------------
#define LGKM0()   asm volatile("s_waitcnt lgkmcnt(0)" ::: "memory")

__global__ __launch_bounds__(192)
__attribute__((amdgpu_waves_per_eu(1, 1)))
void k_fused(
    const unsigned short* __restrict__ xg, const float* __restrict__ Wh,
    const float* __restrict__ bg, float* __restrict__ h_t,
    const unsigned short* __restrict__ tokpad,
    const unsigned short* __restrict__ c1wT, const float* __restrict__ c1b,
    const unsigned short* __restrict__ c2wT, const float* __restrict__ c2b,
    unsigned short* __restrict__ c2o)
{
  __shared__ __align__(16) unsigned short pool[39744];
  int bid = blockIdx.x;
  int tid = threadIdx.x;

  if (bid < 64) {
    // ================= GRU scan (R14: 1 wave, 1 x-stream) ================
    if (tid >= 64) return;                // single-wave scan; waves 1,2 exit
    float* hb = (float*)pool;             // 64-float h buffer
    int b = bid;
    int j = tid;                          // hidden index 0..63

    // Weights: lane j holds Wh[:, j] (z), Wh[:, 64+j] (r), Wh[:, 128+j] (h)
#define DECL_W3(i) \
    float4 wz##i = {Wh[(4*i+0)*192+j],     Wh[(4*i+1)*192+j],     Wh[(4*i+2)*192+j],     Wh[(4*i+3)*192+j]}; \
    float4 wr##i = {Wh[(4*i+0)*192+64+j],  Wh[(4*i+1)*192+64+j],  Wh[(4*i+2)*192+64+j],  Wh[(4*i+3)*192+64+j]}; \
    float4 wh##i = {Wh[(4*i+0)*192+128+j], Wh[(4*i+1)*192+128+j], Wh[(4*i+2)*192+128+j], Wh[(4*i+3)*192+128+j]};
    DECL_W3(0)  DECL_W3(1)  DECL_W3(2)  DECL_W3(3)
    DECL_W3(4)  DECL_W3(5)  DECL_W3(6)  DECL_W3(7)
    DECL_W3(8)  DECL_W3(9)  DECL_W3(10) DECL_W3(11)
    DECL_W3(12) DECL_W3(13) DECL_W3(14) DECL_W3(15)
#undef DECL_W3
#define OPAQ1(V) asm volatile("" : "+v"(V.x), "+v"(V.y), "+v"(V.z), "+v"(V.w));
#define OPAQ3(i) OPAQ1(wz##i) OPAQ1(wr##i) OPAQ1(wh##i)
    OPAQ3(0)  OPAQ3(1)  OPAQ3(2)  OPAQ3(3)
    OPAQ3(4)  OPAQ3(5)  OPAQ3(6)  OPAQ3(7)
    OPAQ3(8)  OPAQ3(9)  OPAQ3(10) OPAQ3(11)
    OPAQ3(12) OPAQ3(13) OPAQ3(14) OPAQ3(15)
#undef OPAQ3
#undef OPAQ1
    float biasz = bg[192 + j];
    float biasr = bg[192 + 64 + j];
    float biash = bg[192 + 128 + j];
    float hreg = 0.f;
    hb[j] = 0.f;
    LGKM0();

    const uint4* xp = (const uint4*)(xg + (size_t)(b * 64 + j) * L_ * 4);
    const float4* hl4 = (const float4*)hb;

    uint4 cur = xp[0];
    uint4 nxt = xp[1];

#define MCH(i) \
    h4 = hl4[i]; \
    az0 = fmaf(h4.x, wz##i.x, az0); az1 = fmaf(h4.y, wz##i.y, az1); az2 = fmaf(h4.z, wz##i.z, az2); az3 = fmaf(h4.w, wz##i.w, az3); \
    ar0 = fmaf(h4.x, wr##i.x, ar0); ar1 = fmaf(h4.y, wr##i.y, ar1); ar2 = fmaf(h4.z, wr##i.z, ar2); ar3 = fmaf(h4.w, wr##i.w, ar3); \
    ah0 = fmaf(h4.x, wh##i.x, ah0); ah1 = fmaf(h4.y, wh##i.y, ah1); ah2 = fmaf(h4.z, wh##i.z, ah2); ah3 = fmaf(h4.w, wh##i.w, ah3);

#define STEP(WZR, WH) { \
    float az0 = biasz, az1 = 0.f, az2 = 0.f, az3 = 0.f; \
    float ar0 = biasr, ar1 = 0.f, ar2 = 0.f, ar3 = 0.f; \
    float ah0 = biash, ah1 = 0.f, ah2 = 0.f, ah3 = 0.f; \
    { float4 h4; \
      MCH(0)  MCH(1)  MCH(2)  MCH(3) \
      MCH(4)  MCH(5)  MCH(6)  MCH(7) \
      MCH(8)  MCH(9)  MCH(10) MCH(11) \
      MCH(12) MCH(13) MCH(14) MCH(15) } \
    float sz = (az0 + az1) + (az2 + az3); \
    float sr = (ar0 + ar1) + (ar2 + ar3); \
    float sh = (ah0 + ah1) + (ah2 + ah3); \
    float xvz = bf2f((unsigned short)((WZR) & 0xffffu)); \
    float xvr = bf2f((unsigned short)((WZR) >> 16)); \
    float xvh = bf2f((unsigned short)((WH) & 0xffffu)); \
    float zg = 1.f / (1.f + __expf(-(xvz + sz))); \
    float rg = 1.f / (1.f + __expf(-(xvr + sr))); \
    float e2 = __expf(-2.f * (xvh + rg * sh)); \
    float hh = fmaf(2.f, __frcp_rn(1.f + e2), -1.f); \
    hreg = zg * hreg + (1.f - zg) * hh; \
    hb[j] = hreg; \
    LGKM0(); \
  }

    #pragma nounroll
    for (int p = 0; p < L_ / 2; ++p) {
      int pn = (p < L_ / 2 - 2) ? p + 2 : (L_ / 2 - 1);
      uint4 nn = xp[pn];
      STEP(cur.x, cur.y)                  // step 2p
      STEP(cur.z, cur.w)                  // step 2p+1
      cur = nxt; nxt = nn;
    }
#undef STEP
#undef MCH
    h_t[b * 64 + j] = hreg;
    return;
  }

  // ================= fused conv1+conv2 (halo recompute) =================
  unsigned short* At    = pool;           // 152 x 136 shorts = 41344 B
  unsigned short* l1buf = pool + 20672;   // 144 x 72  shorts = 20736 B
  unsigned short* Bw    = pool + 31040;   //  64 x 136 shorts = 17408 B
  int wv = tid >> 6, lane = tid & 63;
  int m = lane & 15, q = lane >> 4;

  for (int job = bid - 64; job < 1024; job += 192) {
    int b = job >> 4;
    int l0 = (job & 15) << 7;
    __syncthreads();                      // prev job fully consumed
    for (int i = tid; i < 152 * 16; i += 192) {
      int row = i >> 4, c8 = i & 15;
      int p = l0 - 3 + row;
      p = p < 0 ? 0 : (p > 2055 ? 2055 : p);
      *((uint4*)&At[row * 136 + c8 * 8]) = ((const uint4*)tokpad)[(b * LP + p) * 16 + c8];
    }
    // ---- conv1: l1 rows [l0-3, l0+140] (9 M-tiles of 16), K=128 ----
    f32x4 acc[3][4];
    #pragma unroll
    for (int mt = 0; mt < 3; ++mt)
      #pragma unroll
      for (int nt = 0; nt < 4; ++nt) acc[mt][nt] = (f32x4){0.f,0.f,0.f,0.f};
    for (int w8 = 0; w8 < 8; ++w8) {
      __syncthreads();
      for (int i = tid; i < 64 * 16; i += 192) {
        int row = i >> 4, c8 = i & 15;
        *((uint4*)&Bw[row * 136 + c8 * 8]) = ((const uint4*)c1wT)[(w8 * 64 + row) * 16 + c8];
      }
      __syncthreads();
      #pragma unroll
      for (int ks = 0; ks < 4; ++ks) {
        int kof = ks * 32 + q * 8;
        short8 a[3], bb[4];
        #pragma unroll
        for (int mt = 0; mt < 3; ++mt) {
          int tl = wv + 3 * mt;
          a[mt] = *(const short8*)&At[(tl * 16 + m + w8) * 136 + kof];
        }
        #pragma unroll
        for (int nt = 0; nt < 4; ++nt)
          bb[nt] = *(const short8*)&Bw[(nt * 16 + m) * 136 + kof];
        #pragma unroll
        for (int mt = 0; mt < 3; ++mt)
          #pragma unroll
          for (int nt = 0; nt < 4; ++nt)
            acc[mt][nt] = __builtin_amdgcn_mfma_f32_16x16x32_bf16(a[mt], bb[nt], acc[mt][nt], 0, 0, 0);
      }
    }
    #pragma unroll
    for (int mt = 0; mt < 3; ++mt) {
      int tl = wv + 3 * mt;
      #pragma unroll
      for (int nt = 0; nt < 4; ++nt) {
        int c = nt * 16 + m;
        float bs = c1b[c];
        #pragma unroll
        for (int r = 0; r < 4; ++r) {
          float v = fmaxf(acc[mt][nt][r] + bs, 0.f);
          l1buf[(tl * 16 + q * 4 + r) * 72 + c] = f2bf(v);
        }
      }
    }
    __syncthreads();
    for (int i2 = tid; i2 < 135 * 8; i2 += 192) {
      int i = i2 >> 3, c8 = i2 & 7;
      int jrow = l0 - 3 + i;
      if (jrow < 0 || jrow > 2047) {
        uint4 z4 = {0u,0u,0u,0u};
        *((uint4*)&l1buf[i * 72 + c8 * 8]) = z4;
      }
    }
    // ---- conv2: out rows [l0, l0+127] (8 M-tiles), K=64 ----
    f32x4 acc2[3][4];
    #pragma unroll
    for (int mt = 0; mt < 3; ++mt)
      #pragma unroll
      for (int nt = 0; nt < 4; ++nt) acc2[mt][nt] = (f32x4){0.f,0.f,0.f,0.f};
    for (int w8 = 0; w8 < 8; ++w8) {
      __syncthreads();
      for (int i = tid; i < 64 * 8; i += 192) {
        int row = i >> 3, c8 = i & 7;
        *((uint4*)&Bw[row * 72 + c8 * 8]) = ((const uint4*)c2wT)[(w8 * 64 + row) * 8 + c8];
      }
      __syncthreads();
      #pragma unroll
      for (int ks = 0; ks < 2; ++ks) {
        int kof = ks * 32 + q * 8;
        short8 a[3], bb[4];
        #pragma unroll
        for (int mt = 0; mt < 3; ++mt) {
          int tl = wv + 3 * mt;
          if (tl < 8)
            a[mt] = *(const short8*)&l1buf[(tl * 16 + m + w8) * 72 + kof];
        }
        #pragma unroll
        for (int nt = 0; nt < 4; ++nt)
          bb[nt] = *(const short8*)&Bw[(nt * 16 + m) * 72 + kof];
        #pragma unroll
        for (int mt = 0; mt < 3; ++mt) {
          int tl = wv + 3 * mt;
          if (tl < 8)
            #pragma unroll
            for (int nt = 0; nt < 4; ++nt)
              acc2[mt][nt] = __builtin_amdgcn_mfma_f32_16x16x32_bf16(a[mt], bb[nt], acc2[mt][nt], 0, 0, 0);
        }
      }
    }
    #pragma unroll
    for (int mt = 0; mt < 3; ++mt) {
      int tl = wv + 3 * mt;
      if (tl < 8) {
        #pragma unroll
        for (int nt = 0; nt < 4; ++nt) {
          int c = nt * 16 + m;
          float bs = c2b[c];
          #pragma unroll
          for (int r = 0; r < 4; ++r)
            c2o[(size_t)(b * L_ + l0 + tl * 16 + q * 4 + r) * 64 + c] = f2bf(acc2[mt][nt][r] + bs);
        }
      }
    }
  }
}

// ---------------------------------------------------------------------------
// K5: per-batch tail: L2=c2o*h_t -> l2norm -> conv3 -> softmax alpha ->
//     n_hat = sum alpha*tok -> logits = tok.n_hat + bias -> softmax -> out
// ---------------------------------------------------------------------------
__global__ __launch_bounds__(256) void k_final(
    const unsigned short* __restrict__ tokpad, const unsigned short* __restrict__ c2o,
    const float* __restrict__ h_t, const float* __restrict__ c3w,
    const float* __restrict__ c3b, const float* __restrict__ biasg,
    float* __restrict__ out)
{
  __shared__ float Lf[71 * 65];
  __shared__ float a_lds[2048];
  __shared__ float l_lds[2048];
  __shared__ float red[256];
  __shared__ float nred[512];
  __shared__ float nhat[128];
  __shared__ float ht[64];
  __shared__ float c3[512];
  int b = blockIdx.x, tid = threadIdx.x, lane = tid & 63, wave = tid >> 6;
  if (tid < 64) ht[tid] = h_t[b * 64 + tid];
  for (int i = tid; i < 512; i += 256) c3[i] = c3w[i];
  float c3bias = c3b[0];
  __syncthreads();
  // ---- pass 1: a_logits via normalized features + conv3 (tiles of 64 l) ----
  for (int tile = 0; tile < 32; ++tile) {
    int lt = tile << 6;
    for (int i0 = wave; i0 < 71; i0 += 4) {
      int l = lt - 3 + i0;
      float v = 0.f;
      if (l >= 0 && l < L_) v = bf2f(c2o[((size_t)b * L_ + l) * 64 + lane]) * ht[lane];
      float ss = v * v;
      #pragma unroll
      for (int msk = 1; msk < 64; msk <<= 1) ss += __shfl_xor(ss, msk);
      Lf[i0 * 65 + lane] = v * rsqrtf(ss + 1e-12f);
    }
    __syncthreads();
    {
      int u = lane, part = wave;
      float p = 0.f;
      #pragma unroll
      for (int w = 0; w < 8; ++w)
        #pragma unroll
        for (int cc = 0; cc < 16; ++cc) {
          int c = part * 16 + cc;
          p += Lf[(u + w) * 65 + c] * c3[w * 64 + c];
        }
      red[tid] = p;
    }
    __syncthreads();
    if (tid < 64) a_lds[lt + tid] = red[tid] + red[64 + tid] + red[128 + tid] + red[192 + tid] + c3bias;
    __syncthreads();
  }
  // ---- pass 2: softmax alpha over 2048 ----
  {
    float mx = -1e30f;
    for (int i = tid; i < 2048; i += 256) mx = fmaxf(mx, a_lds[i]);
    #pragma unroll
    for (int msk = 1; msk < 64; msk <<= 1) mx = fmaxf(mx, __shfl_xor(mx, msk));
    if (lane == 0) red[wave] = mx;
    __syncthreads();
    mx = fmaxf(fmaxf(red[0], red[1]), fmaxf(red[2], red[3]));
    float sm = 0.f;
    for (int i = tid; i < 2048; i += 256) sm += __expf(a_lds[i] - mx);
    #pragma unroll
    for (int msk = 1; msk < 64; msk <<= 1) sm += __shfl_xor(sm, msk);
    __syncthreads();
    if (lane == 0) red[wave] = sm;
    __syncthreads();
    sm = red[0] + red[1] + red[2] + red[3];
    float inv = 1.f / sm;
    for (int i = tid; i < 2048; i += 256) a_lds[i] = __expf(a_lds[i] - mx) * inv;
    __syncthreads();
  }
  // ---- pass 3: n_hat[128] = sum_l alpha_l * tok[l][:] ----
  {
    int d2 = tid & 63, g = tid >> 6;
    float ax = 0.f, ay = 0.f;
    for (int l = g; l < L_; l += 4) {
      unsigned int uu = *(const unsigned int*)&tokpad[((size_t)b * LP + PAD + l) * 128 + d2 * 2];
      float al = a_lds[l];
      ax += al * bf2f((unsigned short)(uu & 0xffffu));
      ay += al * bf2f((unsigned short)(uu >> 16));
    }
    nred[g * 128 + d2 * 2] = ax;
    nred[g * 128 + d2 * 2 + 1] = ay;
    __syncthreads();
    if (tid < 128) nhat[tid] = nred[tid] + nred[128 + tid] + nred[256 + tid] + nred[384 + tid];
    __syncthreads();
  }
  // ---- pass 4: logits = tok . n_hat + bias ----
  for (int li = 0; li < 8; ++li) {
    int l = li * 256 + tid;
    const uint4* rowp = (const uint4*)&tokpad[((size_t)b * LP + PAD + l) * 128];
    float s = 0.f;
    #pragma unroll
    for (int jj = 0; jj < 16; ++jj) {
      uint4 uu = rowp[jj];
      s += bf2f((unsigned short)(uu.x & 0xffffu)) * nhat[jj*8+0]
         + bf2f((unsigned short)(uu.x >> 16))     * nhat[jj*8+1]
         + bf2f((unsigned short)(uu.y & 0xffffu)) * nhat[jj*8+2]
         + bf2f((unsigned short)(uu.y >> 16))     * nhat[jj*8+3]
         + bf2f((unsigned short)(uu.z & 0xffffu)) * nhat[jj*8+4]
         + bf2f((unsigned short)(uu.z >> 16))     * nhat[jj*8+5]
         + bf2f((unsigned short)(uu.w & 0xffffu)) * nhat[jj*8+6]
         + bf2f((unsigned short)(uu.w >> 16))     * nhat[jj*8+7];
    }
    l_lds[l] = s + biasg[b * L_ + l];
  }
  __syncthreads();
  // ---- pass 5: final softmax -> out ----
  {
    float mx = -1e30f;
    for (int i = tid; i < 2048; i += 256) mx = fmaxf(mx, l_lds[i]);
    #pragma unroll
    for (int msk = 1; msk < 64; msk <<= 1) mx = fmaxf(mx, __shfl_xor(mx, msk));
    __syncthreads();
    if (lane == 0) red[wave] = mx;
    __syncthreads();
    mx = fmaxf(fmaxf(red[0], red[1]), fmaxf(red[2], red[3]));
    float sm = 0.f;
    for (int i = tid; i < 2048; i += 256) sm += __expf(l_lds[i] - mx);
    #pragma unroll
    for (int msk = 1; msk < 64; msk <<= 1) sm += __shfl_xor(sm, msk);
    __syncthreads();
    if (lane == 0) red[wave] = sm;
    __syncthreads();
    sm = red[0] + red[1] + red[2] + red[3];
    float inv = 1.f / sm;
    for (int i = tid; i < 2048; i += 256) out[b * L_ + i] = __expf(l_lds[i] - mx) * inv;
  }
}

// ---------------------------------------------------------------------------
extern "C" void kernel_launch(void* const* d_in, const int* in_sizes, int n_in,
                              void* d_out, int out_size, void* d_ws, size_t ws_size,
                              hipStream_t stream) {
  const int*   code = (const int*)d_in[0];
  const float* E    = (const float*)d_in[1];
  const float* bt   = (const float*)d_in[2];
  const float* Wx   = (const float*)d_in[3];
  const float* Wh   = (const float*)d_in[4];
  const float* bg   = (const float*)d_in[5];
  const float* c1w  = (const float*)d_in[6];
  const float* c1b  = (const float*)d_in[7];
  const float* c2w  = (const float*)d_in[8];
  const float* c2b  = (const float*)d_in[9];
  const float* c3w  = (const float*)d_in[10];
  const float* c3b  = (const float*)d_in[11];
  char* ws = (char*)d_ws;
  unsigned short* tokpad = (unsigned short*)(ws);               // 33,685,504 B
  unsigned short* xg     = (unsigned short*)(ws + 33685504);    // 67,108,864 B
  unsigned short* c2o    = (unsigned short*)(ws + 100794368);   // 16,777,216 B
  unsigned short* WxT    = (unsigned short*)(ws + 117571584);   //     49,152 B
  unsigned short* c1wT   = (unsigned short*)(ws + 117620736);   //    131,072 B
  unsigned short* c2wT   = (unsigned short*)(ws + 117751808);   //     65,536 B
  float*          htp    = (float*)(ws + 117817344);            //     16,384 B
  float*          biasg  = (float*)(ws + 117833728);            //    524,288 B
  // total ws use: 118,358,016 B

  k_prep <<<9216, 256, 0, stream>>>(code, E, bt, Wx, c1w, c2w, tokpad, WxT, c1wT, c2wT, biasg);
  k_xproj<<<1024, 256, 0, stream>>>(tokpad, WxT, bg, xg);
  k_fused<<<256, 192, 0, stream>>>(xg, Wh, bg, htp, tokpad, c1wT, c1b, c2wT, c2b, c2o);
  k_final<<<64, 256, 0, stream>>>(tokpad, c2o, htp, c3w, c3b, biasg, (float*)d_out);
}

// Round 5
// 1574.139 us; speedup vs baseline: 1.4968x; 1.1242x over previous
//
#include <hip/hip_runtime.h>

#define B_ 64
#define L_ 2048
#define D_ 128
#define LP 2056   // padded rows per batch (3 left, 5 right incl. alignment)
#define PAD 3     // SAME-pad left for W=8

typedef __attribute__((ext_vector_type(8))) short short8;
typedef __attribute__((ext_vector_type(4))) float f32x4;
typedef __attribute__((ext_vector_type(4))) unsigned short us4;

static __device__ __forceinline__ float bf2f(unsigned short u) {
  return __uint_as_float(((unsigned int)u) << 16);
}
static __device__ __forceinline__ unsigned short f2bf(float f) {
  unsigned int x = __float_as_uint(f);
  unsigned int r = (x + 0x7fffu + ((x >> 16) & 1u)) >> 16;  // RNE
  return (unsigned short)r;
}

// ---------------------------------------------------------------------------
// K0: gather tok -> bf16 padded [B,LP,128]; gather bias; transpose weights.
// ---------------------------------------------------------------------------
__global__ __launch_bounds__(256) void k_prep(
    const int* __restrict__ code, const float* __restrict__ E,
    const float* __restrict__ bias_table, const float* __restrict__ Wx,
    const float* __restrict__ c1w, const float* __restrict__ c2w,
    unsigned short* __restrict__ tokpad,
    unsigned short* __restrict__ WxT, unsigned short* __restrict__ c1wT,
    unsigned short* __restrict__ c2wT, float* __restrict__ biasg)
{
  int id = blockIdx.x * 256 + threadIdx.x;
  const int N0 = B_ * LP * 16;            // tokpad in uint4 (8 bf16) chunks
  if (id < N0) {
    int b = id / (LP * 16); int rem = id % (LP * 16);
    int row = rem >> 4, c8 = rem & 15;
    uint4 o = {0u,0u,0u,0u};
    if (row >= PAD && row < PAD + L_) {
      int cd = code[b * L_ + (row - PAD)];
      const float4* e = (const float4*)(E + (size_t)cd * D_ + c8 * 8);
      float4 e0 = e[0], e1 = e[1];
      o.x = f2bf(e0.x) | ((unsigned int)f2bf(e0.y) << 16);
      o.y = f2bf(e0.z) | ((unsigned int)f2bf(e0.w) << 16);
      o.z = f2bf(e1.x) | ((unsigned int)f2bf(e1.y) << 16);
      o.w = f2bf(e1.z) | ((unsigned int)f2bf(e1.w) << 16);
    }
    ((uint4*)tokpad)[id] = o;
    return;
  }
  id -= N0;
  const int N2 = B_ * L_;
  if (id < N2) { biasg[id] = bias_table[code[id]]; return; }
  id -= N2;
  const int N3 = 192 * 128;               // WxT[c][d]
  if (id < N3) { int c = id >> 7, d = id & 127; WxT[id] = f2bf(Wx[d * 192 + c]); return; }
  id -= N3;
  const int N4 = 8 * 64 * 128;            // c1wT[w][c][d]
  if (id < N4) {
    int w = id >> 13, c = (id >> 7) & 63, d = id & 127;
    c1wT[id] = f2bf(c1w[(w * 128 + d) * 64 + c]); return;
  }
  id -= N4;
  const int N5 = 8 * 64 * 64;             // c2wT[w][c][d]
  if (id < N5) {
    int w = id >> 12, c = (id >> 6) & 63, d = id & 63;
    c2wT[id] = f2bf(c2w[(w * 64 + d) * 64 + c]);
  }
}

// ---------------------------------------------------------------------------
// K1: x_proj = tok @ Wx + b_gru[0] -> bf16, GATE-INTERLEAVED per lane:
// xg[b][j][t][{z,r,h,0}] (8 B per step). Same C bits as the R10 kernel
// (same acc, same f2bf); only placement changed so a GRU lane reads ONE
// stream (uint4 = 2 steps).
// ---------------------------------------------------------------------------
__global__ __launch_bounds__(256) void k_xproj(
    const unsigned short* __restrict__ tokpad, const unsigned short* __restrict__ WxT,
    const float* __restrict__ bg, unsigned short* __restrict__ xg)
{
  __shared__ __align__(16) unsigned short At[128 * 136];
  __shared__ __align__(16) unsigned short Bt[192 * 136];
  int b = blockIdx.x >> 4;
  int l0 = (blockIdx.x & 15) << 7;
  int tid = threadIdx.x;
  for (int i = tid; i < 128 * 16; i += 256) {
    int row = i >> 4, c8 = i & 15;
    uint4 v = ((const uint4*)tokpad)[(b * LP + PAD + l0 + row) * 16 + c8];
    *((uint4*)&At[row * 136 + c8 * 8]) = v;
  }
  for (int i = tid; i < 192 * 16; i += 256) {
    int row = i >> 4, c8 = i & 15;
    uint4 v = ((const uint4*)WxT)[i];
    *((uint4*)&Bt[row * 136 + c8 * 8]) = v;
  }
  __syncthreads();
  int wave = tid >> 6, lane = tid & 63;
  int m = lane & 15, q = lane >> 4;
  f32x4 acc[2][12];
  #pragma unroll
  for (int mt = 0; mt < 2; ++mt)
    #pragma unroll
    for (int nt = 0; nt < 12; ++nt) acc[mt][nt] = (f32x4){0.f,0.f,0.f,0.f};
  #pragma unroll
  for (int ks = 0; ks < 4; ++ks) {
    int kof = ks * 32 + q * 8;
    short8 a[2], bb[12];
    #pragma unroll
    for (int mt = 0; mt < 2; ++mt)
      a[mt] = *(const short8*)&At[(wave * 32 + mt * 16 + m) * 136 + kof];
    #pragma unroll
    for (int nt = 0; nt < 12; ++nt)
      bb[nt] = *(const short8*)&Bt[(nt * 16 + m) * 136 + kof];
    #pragma unroll
    for (int mt = 0; mt < 2; ++mt)
      #pragma unroll
      for (int nt = 0; nt < 12; ++nt)
        acc[mt][nt] = __builtin_amdgcn_mfma_f32_16x16x32_bf16(a[mt], bb[nt], acc[mt][nt], 0, 0, 0);
  }
  __syncthreads();                        // all MFMA reads of Bt done
  // deposit C (+bias, bf16) transposed into Bt[c][l]  (l = 0..127)
  #pragma unroll
  for (int mt = 0; mt < 2; ++mt) {
    int lrow = wave * 32 + mt * 16 + q * 4;
    #pragma unroll
    for (int nt = 0; nt < 12; ++nt) {
      int c = nt * 16 + m;                 // C col = lane&15
      float b0 = bg[c];
      us4 val;
      val.x = f2bf(acc[mt][nt][0] + b0);
      val.y = f2bf(acc[mt][nt][1] + b0);
      val.z = f2bf(acc[mt][nt][2] + b0);
      val.w = f2bf(acc[mt][nt][3] + b0);
      *((us4*)&Bt[c * 136 + lrow]) = val;
    }
  }
  __syncthreads();
  // gate-interleaved write-out: per (j, 4-step group): read z/r/h 4-wide,
  // pack [z|r<<16, h] per step, store 2 x uint4 (32 B contiguous per lane).
  for (int i = tid; i < 64 * 32; i += 256) {
    int j = i >> 5, g = i & 31;           // steps l = 4g..4g+3
    us4 z4 = *(const us4*)&Bt[j * 136 + g * 4];
    us4 r4 = *(const us4*)&Bt[(64 + j) * 136 + g * 4];
    us4 h4 = *(const us4*)&Bt[(128 + j) * 136 + g * 4];
    uint4 o0, o1;
    o0.x = (unsigned)z4.x | ((unsigned)r4.x << 16); o0.y = (unsigned)h4.x;
    o0.z = (unsigned)z4.y | ((unsigned)r4.y << 16); o0.w = (unsigned)h4.y;
    o1.x = (unsigned)z4.z | ((unsigned)r4.z << 16); o1.y = (unsigned)h4.z;
    o1.z = (unsigned)z4.w | ((unsigned)r4.w << 16); o1.w = (unsigned)h4.w;
    size_t stp = (size_t)(b * 64 + j) * L_ + l0 + g * 4;  // step index
    ((uint4*)xg)[stp >> 1]       = o0;
    ((uint4*)xg)[(stp >> 1) + 1] = o1;
  }
}

// ---------------------------------------------------------------------------
// K2 (fused): blocks 0..63 = GRU scan; blocks 64..255 = conv1+conv2 with
// halo recompute (l1 LDS-only, identical bf16 rounding). No cross-block deps.
//
// R15 GRU: 2-wave K-SPLIT. R14 showed the 1-wave design's 192 weight regs
// get parked in AGPRs (VGPR_Count=160) with per-use accvgpr shuffling ->
// issue-bound at ~1380 cyc/step. Here wave w owns h[32w..32w+32): lane j
// holds Wh[32w..32w+31, {j,64+j,128+j}] = 96 f32 regs (total demand ~150,
// far under the AGPR cliff). Per step: 96 fma vs 8 broadcast ds_read_b128
// of OWN half (2 SIMDs in parallel) -> write float4 partial (pz,pr,ph) ->
// ONE barrier (parity dbuf) -> read other wave's partial -> s = p0+p1
// (2-operand add commutes bitwise, so both waves get identical bits) ->
// gates+update computed redundantly -> own-wave h write (lgkmcnt only).
// Numerics: only change vs R10 is dot-product association ((bias+lo)+hi);
// f32 reassoc noise ~1e-7 rel, far under bf16 quantization already passed.
// Wave 2 spins L_ matching barriers, then exits.
// ---------------------------------------------------------------------------
#define BARRIER() asm volatile("s_waitcnt lgkmcnt(0)\n\ts_barrier" ::: "memory")
#define LGKM0()   asm volatile("s_waitcnt lgkmcnt(0)" ::: "memory")

__global__ __launch_bounds__(192)
__attribute__((amdgpu_waves_per_eu(1, 1)))
void k_fused(
    const unsigned short* __restrict__ xg, const float* __restrict__ Wh,
    const float* __restrict__ bg, float* __restrict__ h_t,
    const unsigned short* __restrict__ tokpad,
    const unsigned short* __restrict__ c1wT, const float* __restrict__ c1b,
    const unsigned short* __restrict__ c2wT, const float* __restrict__ c2b,
    unsigned short* __restrict__ c2o)
{
  __shared__ __align__(16) unsigned short pool[39744];
  int bid = blockIdx.x;
  int tid = threadIdx.x;

  if (bid < 64) {
    // ================= GRU scan (R15: 2-wave k-split) ====================
    int w = tid >> 6, j = tid & 63;
    if (w == 2) {                         // barrier-matching spin, then out
      for (int s = 0; s < L_; ++s) __builtin_amdgcn_s_barrier();
      return;
    }
    // LDS: [0..127] two own-wave h copies; [128..1151] exchange
    // (2 parities x 2 waves x 64 lanes x float4).
    float* hb  = (float*)pool + w * 64;   // this wave's h copy (full 64)
    float* xch = (float*)pool + 128;
    int b = bid;
    int kb = w * 32;                      // k-rows this wave owns

    // lane j, wave w: Wh rows kb..kb+31, cols j (z), 64+j (r), 128+j (h)
#define DECL_W3(i) \
    float4 wz##i = {Wh[(kb+4*i+0)*192+j],     Wh[(kb+4*i+1)*192+j],     Wh[(kb+4*i+2)*192+j],     Wh[(kb+4*i+3)*192+j]}; \
    float4 wr##i = {Wh[(kb+4*i+0)*192+64+j],  Wh[(kb+4*i+1)*192+64+j],  Wh[(kb+4*i+2)*192+64+j],  Wh[(kb+4*i+3)*192+64+j]}; \
    float4 wh##i = {Wh[(kb+4*i+0)*192+128+j], Wh[(kb+4*i+1)*192+128+j], Wh[(kb+4*i+2)*192+128+j], Wh[(kb+4*i+3)*192+128+j]};
    DECL_W3(0) DECL_W3(1) DECL_W3(2) DECL_W3(3)
    DECL_W3(4) DECL_W3(5) DECL_W3(6) DECL_W3(7)
#undef DECL_W3
#define OPAQ1(V) asm volatile("" : "+v"(V.x), "+v"(V.y), "+v"(V.z), "+v"(V.w));
#define OPAQ3(i) OPAQ1(wz##i) OPAQ1(wr##i) OPAQ1(wh##i)
    OPAQ3(0) OPAQ3(1) OPAQ3(2) OPAQ3(3)
    OPAQ3(4) OPAQ3(5) OPAQ3(6) OPAQ3(7)
#undef OPAQ3
#undef OPAQ1
    // bias seeds: only the low half (wave 0) carries the bias.
    float seedz = (w == 0) ? bg[192 + j]       : 0.f;
    float seedr = (w == 0) ? bg[192 + 64 + j]  : 0.f;
    float seedh = (w == 0) ? bg[192 + 128 + j] : 0.f;
    float hreg = 0.f;
    hb[j] = 0.f;
    LGKM0();

    const uint4* xp = (const uint4*)(xg + (size_t)(b * 64 + j) * L_ * 4);
    const float4* hl4 = (const float4*)(hb + kb);   // own half of own copy
    float* xs_mine  = xch + (w * 64 + j) * 4;       // + P*512
    const float* xs_other = xch + ((1 - w) * 64 + j) * 4;

    uint4 cur_ = xp[0];
    uint4 nxt_ = xp[1];

#define MCH(i) \
    h4 = hl4[i]; \
    az0 = fmaf(h4.x, wz##i.x, az0); az1 = fmaf(h4.y, wz##i.y, az1); az2 = fmaf(h4.z, wz##i.z, az2); az3 = fmaf(h4.w, wz##i.w, az3); \
    ar0 = fmaf(h4.x, wr##i.x, ar0); ar1 = fmaf(h4.y, wr##i.y, ar1); ar2 = fmaf(h4.z, wr##i.z, ar2); ar3 = fmaf(h4.w, wr##i.w, ar3); \
    ah0 = fmaf(h4.x, wh##i.x, ah0); ah1 = fmaf(h4.y, wh##i.y, ah1); ah2 = fmaf(h4.z, wh##i.z, ah2); ah3 = fmaf(h4.w, wh##i.w, ah3);

#define STEP(WZR, WH, P) { \
    float az0 = seedz, az1 = 0.f, az2 = 0.f, az3 = 0.f; \
    float ar0 = seedr, ar1 = 0.f, ar2 = 0.f, ar3 = 0.f; \
    float ah0 = seedh, ah1 = 0.f, ah2 = 0.f, ah3 = 0.f; \
    { float4 h4; \
      MCH(0) MCH(1) MCH(2) MCH(3) \
      MCH(4) MCH(5) MCH(6) MCH(7) } \
    float4 pv; \
    pv.x = (az0 + az1) + (az2 + az3); \
    pv.y = (ar0 + ar1) + (ar2 + ar3); \
    pv.z = (ah0 + ah1) + (ah2 + ah3); \
    pv.w = 0.f; \
    *((float4*)(xs_mine + (P) * 512)) = pv; \
    BARRIER(); \
    float4 ov = *((const float4*)(xs_other + (P) * 512)); \
    float sz = pv.x + ov.x; \
    float sr = pv.y + ov.y; \
    float sh = pv.z + ov.z; \
    float xvz = bf2f((unsigned short)((WZR) & 0xffffu)); \
    float xvr = bf2f((unsigned short)((WZR) >> 16)); \
    float xvh = bf2f((unsigned short)((WH) & 0xffffu)); \
    float zg = 1.f / (1.f + __expf(-(xvz + sz))); \
    float rg = 1.f / (1.f + __expf(-(xvr + sr))); \
    float e2 = __expf(-2.f * (xvh + rg * sh)); \
    float hh = fmaf(2.f, __frcp_rn(1.f + e2), -1.f); \
    hreg = zg * hreg + (1.f - zg) * hh; \
    hb[j] = hreg; \
    LGKM0(); \
  }

    #pragma nounroll
    for (int p = 0; p < L_ / 2; ++p) {
      int pn = (p < L_ / 2 - 2) ? p + 2 : (L_ / 2 - 1);
      uint4 nn = xp[pn];
      STEP(cur_.x, cur_.y, 0)
      STEP(cur_.z, cur_.w, 1)
      cur_ = nxt_; nxt_ = nn;
    }
#undef STEP
#undef MCH
    if (w == 0) h_t[b * 64 + j] = hreg;
    return;
  }

  // ================= fused conv1+conv2 (halo recompute) =================
  unsigned short* At    = pool;           // 152 x 136 shorts = 41344 B
  unsigned short* l1buf = pool + 20672;   // 144 x 72  shorts = 20736 B
  unsigned short* Bw    = pool + 31040;   //  64 x 136 shorts = 17408 B
  int wv = tid >> 6, lane = tid & 63;
  int m = lane & 15, q = lane >> 4;

  for (int job = bid - 64; job < 1024; job += 192) {
    int b = job >> 4;
    int l0 = (job & 15) << 7;
    __syncthreads();                      // prev job fully consumed
    for (int i = tid; i < 152 * 16; i += 192) {
      int row = i >> 4, c8 = i & 15;
      int p = l0 - 3 + row;
      p = p < 0 ? 0 : (p > 2055 ? 2055 : p);
      *((uint4*)&At[row * 136 + c8 * 8]) = ((const uint4*)tokpad)[(b * LP + p) * 16 + c8];
    }
    // ---- conv1: l1 rows [l0-3, l0+140] (9 M-tiles of 16), K=128 ----
    f32x4 acc[3][4];
    #pragma unroll
    for (int mt = 0; mt < 3; ++mt)
      #pragma unroll
      for (int nt = 0; nt < 4; ++nt) acc[mt][nt] = (f32x4){0.f,0.f,0.f,0.f};
    for (int w8 = 0; w8 < 8; ++w8) {
      __syncthreads();
      for (int i = tid; i < 64 * 16; i += 192) {
        int row = i >> 4, c8 = i & 15;
        *((uint4*)&Bw[row * 136 + c8 * 8]) = ((const uint4*)c1wT)[(w8 * 64 + row) * 16 + c8];
      }
      __syncthreads();
      #pragma unroll
      for (int ks = 0; ks < 4; ++ks) {
        int kof = ks * 32 + q * 8;
        short8 a[3], bb[4];
        #pragma unroll
        for (int mt = 0; mt < 3; ++mt) {
          int tl = wv + 3 * mt;
          a[mt] = *(const short8*)&At[(tl * 16 + m + w8) * 136 + kof];
        }
        #pragma unroll
        for (int nt = 0; nt < 4; ++nt)
          bb[nt] = *(const short8*)&Bw[(nt * 16 + m) * 136 + kof];
        #pragma unroll
        for (int mt = 0; mt < 3; ++mt)
          #pragma unroll
          for (int nt = 0; nt < 4; ++nt)
            acc[mt][nt] = __builtin_amdgcn_mfma_f32_16x16x32_bf16(a[mt], bb[nt], acc[mt][nt], 0, 0, 0);
      }
    }
    #pragma unroll
    for (int mt = 0; mt < 3; ++mt) {
      int tl = wv + 3 * mt;
      #pragma unroll
      for (int nt = 0; nt < 4; ++nt) {
        int c = nt * 16 + m;
        float bs = c1b[c];
        #pragma unroll
        for (int r = 0; r < 4; ++r) {
          float v = fmaxf(acc[mt][nt][r] + bs, 0.f);
          l1buf[(tl * 16 + q * 4 + r) * 72 + c] = f2bf(v);
        }
      }
    }
    __syncthreads();
    for (int i2 = tid; i2 < 135 * 8; i2 += 192) {
      int i = i2 >> 3, c8 = i2 & 7;
      int jrow = l0 - 3 + i;
      if (jrow < 0 || jrow > 2047) {
        uint4 z4 = {0u,0u,0u,0u};
        *((uint4*)&l1buf[i * 72 + c8 * 8]) = z4;
      }
    }
    // ---- conv2: out rows [l0, l0+127] (8 M-tiles), K=64 ----
    f32x4 acc2[3][4];
    #pragma unroll
    for (int mt = 0; mt < 3; ++mt)
      #pragma unroll
      for (int nt = 0; nt < 4; ++nt) acc2[mt][nt] = (f32x4){0.f,0.f,0.f,0.f};
    for (int w8 = 0; w8 < 8; ++w8) {
      __syncthreads();
      for (int i = tid; i < 64 * 8; i += 192) {
        int row = i >> 3, c8 = i & 7;
        *((uint4*)&Bw[row * 72 + c8 * 8]) = ((const uint4*)c2wT)[(w8 * 64 + row) * 8 + c8];
      }
      __syncthreads();
      #pragma unroll
      for (int ks = 0; ks < 2; ++ks) {
        int kof = ks * 32 + q * 8;
        short8 a[3], bb[4];
        #pragma unroll
        for (int mt = 0; mt < 3; ++mt) {
          int tl = wv + 3 * mt;
          if (tl < 8)
            a[mt] = *(const short8*)&l1buf[(tl * 16 + m + w8) * 72 + kof];
        }
        #pragma unroll
        for (int nt = 0; nt < 4; ++nt)
          bb[nt] = *(const short8*)&Bw[(nt * 16 + m) * 72 + kof];
        #pragma unroll
        for (int mt = 0; mt < 3; ++mt) {
          int tl = wv + 3 * mt;
          if (tl < 8)
            #pragma unroll
            for (int nt = 0; nt < 4; ++nt)
              acc2[mt][nt] = __builtin_amdgcn_mfma_f32_16x16x32_bf16(a[mt], bb[nt], acc2[mt][nt], 0, 0, 0);
        }
      }
    }
    #pragma unroll
    for (int mt = 0; mt < 3; ++mt) {
      int tl = wv + 3 * mt;
      if (tl < 8) {
        #pragma unroll
        for (int nt = 0; nt < 4; ++nt) {
          int c = nt * 16 + m;
          float bs = c2b[c];
          #pragma unroll
          for (int r = 0; r < 4; ++r)
            c2o[(size_t)(b * L_ + l0 + tl * 16 + q * 4 + r) * 64 + c] = f2bf(acc2[mt][nt][r] + bs);
        }
      }
    }
  }
}

// ---------------------------------------------------------------------------
// K5: per-batch tail: L2=c2o*h_t -> l2norm -> conv3 -> softmax alpha ->
//     n_hat = sum alpha*tok -> logits = tok.n_hat + bias -> softmax -> out
// ---------------------------------------------------------------------------
__global__ __launch_bounds__(256) void k_final(
    const unsigned short* __restrict__ tokpad, const unsigned short* __restrict__ c2o,
    const float* __restrict__ h_t, const float* __restrict__ c3w,
    const float* __restrict__ c3b, const float* __restrict__ biasg,
    float* __restrict__ out)
{
  __shared__ float Lf[71 * 65];
  __shared__ float a_lds[2048];
  __shared__ float l_lds[2048];
  __shared__ float red[256];
  __shared__ float nred[512];
  __shared__ float nhat[128];
  __shared__ float ht[64];
  __shared__ float c3[512];
  int b = blockIdx.x, tid = threadIdx.x, lane = tid & 63, wave = tid >> 6;
  if (tid < 64) ht[tid] = h_t[b * 64 + tid];
  for (int i = tid; i < 512; i += 256) c3[i] = c3w[i];
  float c3bias = c3b[0];
  __syncthreads();
  // ---- pass 1: a_logits via normalized features + conv3 (tiles of 64 l) ----
  for (int tile = 0; tile < 32; ++tile) {
    int lt = tile << 6;
    for (int i0 = wave; i0 < 71; i0 += 4) {
      int l = lt - 3 + i0;
      float v = 0.f;
      if (l >= 0 && l < L_) v = bf2f(c2o[((size_t)b * L_ + l) * 64 + lane]) * ht[lane];
      float ss = v * v;
      #pragma unroll
      for (int msk = 1; msk < 64; msk <<= 1) ss += __shfl_xor(ss, msk);
      Lf[i0 * 65 + lane] = v * rsqrtf(ss + 1e-12f);
    }
    __syncthreads();
    {
      int u = lane, part = wave;
      float p = 0.f;
      #pragma unroll
      for (int w = 0; w < 8; ++w)
        #pragma unroll
        for (int cc = 0; cc < 16; ++cc) {
          int c = part * 16 + cc;
          p += Lf[(u + w) * 65 + c] * c3[w * 64 + c];
        }
      red[tid] = p;
    }
    __syncthreads();
    if (tid < 64) a_lds[lt + tid] = red[tid] + red[64 + tid] + red[128 + tid] + red[192 + tid] + c3bias;
    __syncthreads();
  }
  // ---- pass 2: softmax alpha over 2048 ----
  {
    float mx = -1e30f;
    for (int i = tid; i < 2048; i += 256) mx = fmaxf(mx, a_lds[i]);
    #pragma unroll
    for (int msk = 1; msk < 64; msk <<= 1) mx = fmaxf(mx, __shfl_xor(mx, msk));
    if (lane == 0) red[wave] = mx;
    __syncthreads();
    mx = fmaxf(fmaxf(red[0], red[1]), fmaxf(red[2], red[3]));
    float sm = 0.f;
    for (int i = tid; i < 2048; i += 256) sm += __expf(a_lds[i] - mx);
    #pragma unroll
    for (int msk = 1; msk < 64; msk <<= 1) sm += __shfl_xor(sm, msk);
    __syncthreads();
    if (lane == 0) red[wave] = sm;
    __syncthreads();
    sm = red[0] + red[1] + red[2] + red[3];
    float inv = 1.f / sm;
    for (int i = tid; i < 2048; i += 256) a_lds[i] = __expf(a_lds[i] - mx) * inv;
    __syncthreads();
  }
  // ---- pass 3: n_hat[128] = sum_l alpha_l * tok[l][:] ----
  {
    int d2 = tid & 63, g = tid >> 6;
    float ax = 0.f, ay = 0.f;
    for (int l = g; l < L_; l += 4) {
      unsigned int uu = *(const unsigned int*)&tokpad[((size_t)b * LP + PAD + l) * 128 + d2 * 2];
      float al = a_lds[l];
      ax += al * bf2f((unsigned short)(uu & 0xffffu));
      ay += al * bf2f((unsigned short)(uu >> 16));
    }
    nred[g * 128 + d2 * 2] = ax;
    nred[g * 128 + d2 * 2 + 1] = ay;
    __syncthreads();
    if (tid < 128) nhat[tid] = nred[tid] + nred[128 + tid] + nred[256 + tid] + nred[384 + tid];
    __syncthreads();
  }
  // ---- pass 4: logits = tok . n_hat + bias ----
  for (int li = 0; li < 8; ++li) {
    int l = li * 256 + tid;
    const uint4* rowp = (const uint4*)&tokpad[((size_t)b * LP + PAD + l) * 128];
    float s = 0.f;
    #pragma unroll
    for (int jj = 0; jj < 16; ++jj) {
      uint4 uu = rowp[jj];
      s += bf2f((unsigned short)(uu.x & 0xffffu)) * nhat[jj*8+0]
         + bf2f((unsigned short)(uu.x >> 16))     * nhat[jj*8+1]
         + bf2f((unsigned short)(uu.y & 0xffffu)) * nhat[jj*8+2]
         + bf2f((unsigned short)(uu.y >> 16))     * nhat[jj*8+3]
         + bf2f((unsigned short)(uu.z & 0xffffu)) * nhat[jj*8+4]
         + bf2f((unsigned short)(uu.z >> 16))     * nhat[jj*8+5]
         + bf2f((unsigned short)(uu.w & 0xffffu)) * nhat[jj*8+6]
         + bf2f((unsigned short)(uu.w >> 16))     * nhat[jj*8+7];
    }
    l_lds[l] = s + biasg[b * L_ + l];
  }
  __syncthreads();
  // ---- pass 5: final softmax -> out ----
  {
    float mx = -1e30f;
    for (int i = tid; i < 2048; i += 256) mx = fmaxf(mx, l_lds[i]);
    #pragma unroll
    for (int msk = 1; msk < 64; msk <<= 1) mx = fmaxf(mx, __shfl_xor(mx, msk));
    __syncthreads();
    if (lane == 0) red[wave] = mx;
    __syncthreads();
    mx = fmaxf(fmaxf(red[0], red[1]), fmaxf(red[2], red[3]));
    float sm = 0.f;
    for (int i = tid; i < 2048; i += 256) sm += __expf(l_lds[i] - mx);
    #pragma unroll
    for (int msk = 1; msk < 64; msk <<= 1) sm += __shfl_xor(sm, msk);
    __syncthreads();
    if (lane == 0) red[wave] = sm;
    __syncthreads();
    sm = red[0] + red[1] + red[2] + red[3];
    float inv = 1.f / sm;
    for (int i = tid; i < 2048; i += 256) out[b * L_ + i] = __expf(l_lds[i] - mx) * inv;
  }
}

// ---------------------------------------------------------------------------
extern "C" void kernel_launch(void* const* d_in, const int* in_sizes, int n_in,
                              void* d_out, int out_size, void* d_ws, size_t ws_size,
                              hipStream_t stream) {
  const int*   code = (const int*)d_in[0];
  const float* E    = (const float*)d_in[1];
  const float* bt   = (const float*)d_in[2];
  const float* Wx   = (const float*)d_in[3];
  const float* Wh   = (const float*)d_in[4];
  const float* bg   = (const float*)d_in[5];
  const float* c1w  = (const float*)d_in[6];
  const float* c1b  = (const float*)d_in[7];
  const float* c2w  = (const float*)d_in[8];
  const float* c2b  = (const float*)d_in[9];
  const float* c3w  = (const float*)d_in[10];
  const float* c3b  = (const float*)d_in[11];
  char* ws = (char*)d_ws;
  unsigned short* tokpad = (unsigned short*)(ws);               // 33,685,504 B
  unsigned short* xg     = (unsigned short*)(ws + 33685504);    // 67,108,864 B
  unsigned short* c2o    = (unsigned short*)(ws + 100794368);   // 16,777,216 B
  unsigned short* WxT    = (unsigned short*)(ws + 117571584);   //     49,152 B
  unsigned short* c1wT   = (unsigned short*)(ws + 117620736);   //    131,072 B
  unsigned short* c2wT   = (unsigned short*)(ws + 117751808);   //     65,536 B
  float*          htp    = (float*)(ws + 117817344);            //     16,384 B
  float*          biasg  = (float*)(ws + 117833728);            //    524,288 B
  // total ws use: 118,358,016 B

  k_prep <<<9216, 256, 0, stream>>>(code, E, bt, Wx, c1w, c2w, tokpad, WxT, c1wT, c2wT, biasg);
  k_xproj<<<1024, 256, 0, stream>>>(tokpad, WxT, bg, xg);
  k_fused<<<256, 192, 0, stream>>>(xg, Wh, bg, htp, tokpad, c1wT, c1b, c2wT, c2b, c2o);
  k_final<<<64, 256, 0, stream>>>(tokpad, c2o, htp, c3w, c3b, biasg, (float*)d_out);
}

// Round 6
// 1498.322 us; speedup vs baseline: 1.5725x; 1.0506x over previous
//
#include <hip/hip_runtime.h>

#define B_ 64
#define L_ 2048
#define D_ 128
#define LP 2056   // padded rows per batch (3 left, 5 right incl. alignment)
#define PAD 3     // SAME-pad left for W=8

typedef __attribute__((ext_vector_type(8))) short short8;
typedef __attribute__((ext_vector_type(4))) float f32x4;
typedef __attribute__((ext_vector_type(4))) unsigned short us4;

static __device__ __forceinline__ float bf2f(unsigned short u) {
  return __uint_as_float(((unsigned int)u) << 16);
}
static __device__ __forceinline__ unsigned short f2bf(float f) {
  unsigned int x = __float_as_uint(f);
  unsigned int r = (x + 0x7fffu + ((x >> 16) & 1u)) >> 16;  // RNE
  return (unsigned short)r;
}

// ---------------------------------------------------------------------------
// K0: gather tok -> bf16 padded [B,LP,128]; gather bias; transpose weights.
// ---------------------------------------------------------------------------
__global__ __launch_bounds__(256) void k_prep(
    const int* __restrict__ code, const float* __restrict__ E,
    const float* __restrict__ bias_table, const float* __restrict__ Wx,
    const float* __restrict__ c1w, const float* __restrict__ c2w,
    unsigned short* __restrict__ tokpad,
    unsigned short* __restrict__ WxT, unsigned short* __restrict__ c1wT,
    unsigned short* __restrict__ c2wT, float* __restrict__ biasg)
{
  int id = blockIdx.x * 256 + threadIdx.x;
  const int N0 = B_ * LP * 16;            // tokpad in uint4 (8 bf16) chunks
  if (id < N0) {
    int b = id / (LP * 16); int rem = id % (LP * 16);
    int row = rem >> 4, c8 = rem & 15;
    uint4 o = {0u,0u,0u,0u};
    if (row >= PAD && row < PAD + L_) {
      int cd = code[b * L_ + (row - PAD)];
      const float4* e = (const float4*)(E + (size_t)cd * D_ + c8 * 8);
      float4 e0 = e[0], e1 = e[1];
      o.x = f2bf(e0.x) | ((unsigned int)f2bf(e0.y) << 16);
      o.y = f2bf(e0.z) | ((unsigned int)f2bf(e0.w) << 16);
      o.z = f2bf(e1.x) | ((unsigned int)f2bf(e1.y) << 16);
      o.w = f2bf(e1.z) | ((unsigned int)f2bf(e1.w) << 16);
    }
    ((uint4*)tokpad)[id] = o;
    return;
  }
  id -= N0;
  const int N2 = B_ * L_;
  if (id < N2) { biasg[id] = bias_table[code[id]]; return; }
  id -= N2;
  const int N3 = 192 * 128;               // WxT[c][d]
  if (id < N3) { int c = id >> 7, d = id & 127; WxT[id] = f2bf(Wx[d * 192 + c]); return; }
  id -= N3;
  const int N4 = 8 * 64 * 128;            // c1wT[w][c][d]
  if (id < N4) {
    int w = id >> 13, c = (id >> 7) & 63, d = id & 127;
    c1wT[id] = f2bf(c1w[(w * 128 + d) * 64 + c]); return;
  }
  id -= N4;
  const int N5 = 8 * 64 * 64;             // c2wT[w][c][d]
  if (id < N5) {
    int w = id >> 12, c = (id >> 6) & 63, d = id & 63;
    c2wT[id] = f2bf(c2w[(w * 64 + d) * 64 + c]);
  }
}

// ---------------------------------------------------------------------------
// K1: x_proj = tok @ Wx + b_gru[0] -> bf16, GATE-INTERLEAVED per lane:
// xg[b][j][t][{z,r,h,0}] (8 B per step). Same C bits as the R10 kernel
// (same acc, same f2bf); only placement changed so a GRU lane reads ONE
// stream (uint4 = 2 steps).
// ---------------------------------------------------------------------------
__global__ __launch_bounds__(256) void k_xproj(
    const unsigned short* __restrict__ tokpad, const unsigned short* __restrict__ WxT,
    const float* __restrict__ bg, unsigned short* __restrict__ xg)
{
  __shared__ __align__(16) unsigned short At[128 * 136];
  __shared__ __align__(16) unsigned short Bt[192 * 136];
  int b = blockIdx.x >> 4;
  int l0 = (blockIdx.x & 15) << 7;
  int tid = threadIdx.x;
  for (int i = tid; i < 128 * 16; i += 256) {
    int row = i >> 4, c8 = i & 15;
    uint4 v = ((const uint4*)tokpad)[(b * LP + PAD + l0 + row) * 16 + c8];
    *((uint4*)&At[row * 136 + c8 * 8]) = v;
  }
  for (int i = tid; i < 192 * 16; i += 256) {
    int row = i >> 4, c8 = i & 15;
    uint4 v = ((const uint4*)WxT)[i];
    *((uint4*)&Bt[row * 136 + c8 * 8]) = v;
  }
  __syncthreads();
  int wave = tid >> 6, lane = tid & 63;
  int m = lane & 15, q = lane >> 4;
  f32x4 acc[2][12];
  #pragma unroll
  for (int mt = 0; mt < 2; ++mt)
    #pragma unroll
    for (int nt = 0; nt < 12; ++nt) acc[mt][nt] = (f32x4){0.f,0.f,0.f,0.f};
  #pragma unroll
  for (int ks = 0; ks < 4; ++ks) {
    int kof = ks * 32 + q * 8;
    short8 a[2], bb[12];
    #pragma unroll
    for (int mt = 0; mt < 2; ++mt)
      a[mt] = *(const short8*)&At[(wave * 32 + mt * 16 + m) * 136 + kof];
    #pragma unroll
    for (int nt = 0; nt < 12; ++nt)
      bb[nt] = *(const short8*)&Bt[(nt * 16 + m) * 136 + kof];
    #pragma unroll
    for (int mt = 0; mt < 2; ++mt)
      #pragma unroll
      for (int nt = 0; nt < 12; ++nt)
        acc[mt][nt] = __builtin_amdgcn_mfma_f32_16x16x32_bf16(a[mt], bb[nt], acc[mt][nt], 0, 0, 0);
  }
  __syncthreads();                        // all MFMA reads of Bt done
  // deposit C (+bias, bf16) transposed into Bt[c][l]  (l = 0..127)
  #pragma unroll
  for (int mt = 0; mt < 2; ++mt) {
    int lrow = wave * 32 + mt * 16 + q * 4;
    #pragma unroll
    for (int nt = 0; nt < 12; ++nt) {
      int c = nt * 16 + m;                 // C col = lane&15
      float b0 = bg[c];
      us4 val;
      val.x = f2bf(acc[mt][nt][0] + b0);
      val.y = f2bf(acc[mt][nt][1] + b0);
      val.z = f2bf(acc[mt][nt][2] + b0);
      val.w = f2bf(acc[mt][nt][3] + b0);
      *((us4*)&Bt[c * 136 + lrow]) = val;
    }
  }
  __syncthreads();
  // gate-interleaved write-out: per (j, 4-step group): read z/r/h 4-wide,
  // pack [z|r<<16, h] per step, store 2 x uint4 (32 B contiguous per lane).
  for (int i = tid; i < 64 * 32; i += 256) {
    int j = i >> 5, g = i & 31;           // steps l = 4g..4g+3
    us4 z4 = *(const us4*)&Bt[j * 136 + g * 4];
    us4 r4 = *(const us4*)&Bt[(64 + j) * 136 + g * 4];
    us4 h4 = *(const us4*)&Bt[(128 + j) * 136 + g * 4];
    uint4 o0, o1;
    o0.x = (unsigned)z4.x | ((unsigned)r4.x << 16); o0.y = (unsigned)h4.x;
    o0.z = (unsigned)z4.y | ((unsigned)r4.y << 16); o0.w = (unsigned)h4.y;
    o1.x = (unsigned)z4.z | ((unsigned)r4.z << 16); o1.y = (unsigned)h4.z;
    o1.z = (unsigned)z4.w | ((unsigned)r4.w << 16); o1.w = (unsigned)h4.w;
    size_t stp = (size_t)(b * 64 + j) * L_ + l0 + g * 4;  // step index
    ((uint4*)xg)[stp >> 1]       = o0;
    ((uint4*)xg)[(stp >> 1) + 1] = o1;
  }
}

// ---------------------------------------------------------------------------
// K2 (fused): blocks 0..63 = GRU scan; blocks 64..255 = conv1+conv2 with
// halo recompute (l1 LDS-only, identical bf16 rounding). No cross-block deps.
//
// R16 GRU: 3-wave k-split + SGPR-broadcast h. R15 (2-wave, h via LDS round
// trip) sat at ~1150 cyc/step; its h write->wait->broadcast-read chain was
// ~220 cyc, and the 3rd wave was idle. Every lane of every wave holds the
// full h[j] in hreg after the redundant update, so the matvec broadcast is
// done with v_readlane -> SGPR -> v_fma(sgpr,vgpr,vgpr): ZERO h LDS traffic.
// R11's readlane failure was interleaved readlane->fma RAW stalls; here all
// 22 (independent) readlanes issue as a block, fenced from the fmas by
// sched_barrier(0). Wave w owns k-rows 22w..22w+21 (w=2 padded: zero
// weights past k=63; fmaf(h,0,a)==a exactly; readlane idx &63). One LDS
// round trip/step remains: the float4 partial exchange (parity-dbuf, one
// barrier). Partials summed in fixed wave order (p0+p1)+p2 -> bitwise
// identical across waves. f32 k-association changes vs R15 (3-way split);
// R15 proved reassociation is invisible under the bf16 quantization floor.
// ---------------------------------------------------------------------------
#define BARRIER() asm volatile("s_waitcnt lgkmcnt(0)\n\ts_barrier" ::: "memory")

__global__ __launch_bounds__(192)
__attribute__((amdgpu_waves_per_eu(1, 1)))
void k_fused(
    const unsigned short* __restrict__ xg, const float* __restrict__ Wh,
    const float* __restrict__ bg, float* __restrict__ h_t,
    const unsigned short* __restrict__ tokpad,
    const unsigned short* __restrict__ c1wT, const float* __restrict__ c1b,
    const unsigned short* __restrict__ c2wT, const float* __restrict__ c2b,
    unsigned short* __restrict__ c2o)
{
  __shared__ __align__(16) unsigned short pool[39744];
  int bid = blockIdx.x;
  int tid = threadIdx.x;

  if (bid < 64) {
    // ================= GRU scan (R16: 3-wave k-split, readlane h) ========
    int w = tid >> 6, j = tid & 63;
    float* xch = (float*)pool;            // 2 parities x 3 waves x 64 x f32x4
    int b = bid;
    int kb = w * 22;                      // k-rows kb..kb+21 (padded past 63)

    float wz[22], wr[22], wh[22];
    #pragma unroll
    for (int i = 0; i < 22; ++i) {
      int k = kb + i;
      bool ok = k < 64;
      wz[i] = ok ? Wh[k * 192 + j]       : 0.f;
      wr[i] = ok ? Wh[k * 192 + 64 + j]  : 0.f;
      wh[i] = ok ? Wh[k * 192 + 128 + j] : 0.f;
    }
    #pragma unroll
    for (int i = 0; i < 22; ++i)
      asm volatile("" : "+v"(wz[i]), "+v"(wr[i]), "+v"(wh[i]));

    // bias seeds: only wave 0 carries the bias (fixed-order partial sum).
    float seedz = (w == 0) ? bg[192 + j]       : 0.f;
    float seedr = (w == 0) ? bg[192 + 64 + j]  : 0.f;
    float seedh = (w == 0) ? bg[192 + 128 + j] : 0.f;
    float hreg = 0.f;

    const uint4* xp = (const uint4*)(xg + (size_t)(b * 64 + j) * L_ * 4);
    uint4 cur_ = xp[0];
    uint4 nxt_ = xp[1];

#define STEP(WZR, WH_, P) { \
    float hk[22]; \
    _Pragma("unroll") \
    for (int i = 0; i < 22; ++i) \
      hk[i] = __int_as_float(__builtin_amdgcn_readlane(__float_as_int(hreg), (kb + i) & 63)); \
    __builtin_amdgcn_sched_barrier(0); \
    float az[4] = {seedz, 0.f, 0.f, 0.f}; \
    float ar[4] = {seedr, 0.f, 0.f, 0.f}; \
    float ah[4] = {seedh, 0.f, 0.f, 0.f}; \
    _Pragma("unroll") \
    for (int i = 0; i < 22; ++i) { \
      az[i & 3] = fmaf(hk[i], wz[i], az[i & 3]); \
      ar[i & 3] = fmaf(hk[i], wr[i], ar[i & 3]); \
      ah[i & 3] = fmaf(hk[i], wh[i], ah[i & 3]); \
    } \
    float4 pv; \
    pv.x = (az[0] + az[1]) + (az[2] + az[3]); \
    pv.y = (ar[0] + ar[1]) + (ar[2] + ar[3]); \
    pv.z = (ah[0] + ah[1]) + (ah[2] + ah[3]); \
    pv.w = 0.f; \
    *((float4*)&xch[(P) * 768 + (w * 64 + j) * 4]) = pv; \
    BARRIER(); \
    float4 q0 = *((const float4*)&xch[(P) * 768 + (0 * 64 + j) * 4]); \
    float4 q1 = *((const float4*)&xch[(P) * 768 + (1 * 64 + j) * 4]); \
    float4 q2 = *((const float4*)&xch[(P) * 768 + (2 * 64 + j) * 4]); \
    float sz = (q0.x + q1.x) + q2.x; \
    float sr = (q0.y + q1.y) + q2.y; \
    float sh = (q0.z + q1.z) + q2.z; \
    float xvz = bf2f((unsigned short)((WZR) & 0xffffu)); \
    float xvr = bf2f((unsigned short)((WZR) >> 16)); \
    float xvh = bf2f((unsigned short)((WH_) & 0xffffu)); \
    float zg = 1.f / (1.f + __expf(-(xvz + sz))); \
    float rg = 1.f / (1.f + __expf(-(xvr + sr))); \
    float e2 = __expf(-2.f * (xvh + rg * sh)); \
    float hh = fmaf(2.f, __frcp_rn(1.f + e2), -1.f); \
    hreg = zg * hreg + (1.f - zg) * hh; \
  }

    #pragma nounroll
    for (int p = 0; p < L_ / 2; ++p) {
      int pn = (p < L_ / 2 - 2) ? p + 2 : (L_ / 2 - 1);
      uint4 nn = xp[pn];
      STEP(cur_.x, cur_.y, 0)
      STEP(cur_.z, cur_.w, 1)
      cur_ = nxt_; nxt_ = nn;
    }
#undef STEP
    if (w == 0) h_t[b * 64 + j] = hreg;
    return;
  }

  // ================= fused conv1+conv2 (halo recompute) =================
  unsigned short* At    = pool;           // 152 x 136 shorts = 41344 B
  unsigned short* l1buf = pool + 20672;   // 144 x 72  shorts = 20736 B
  unsigned short* Bw    = pool + 31040;   //  64 x 136 shorts = 17408 B
  int wv = tid >> 6, lane = tid & 63;
  int m = lane & 15, q = lane >> 4;

  for (int job = bid - 64; job < 1024; job += 192) {
    int b = job >> 4;
    int l0 = (job & 15) << 7;
    __syncthreads();                      // prev job fully consumed
    for (int i = tid; i < 152 * 16; i += 192) {
      int row = i >> 4, c8 = i & 15;
      int p = l0 - 3 + row;
      p = p < 0 ? 0 : (p > 2055 ? 2055 : p);
      *((uint4*)&At[row * 136 + c8 * 8]) = ((const uint4*)tokpad)[(b * LP + p) * 16 + c8];
    }
    // ---- conv1: l1 rows [l0-3, l0+140] (9 M-tiles of 16), K=128 ----
    f32x4 acc[3][4];
    #pragma unroll
    for (int mt = 0; mt < 3; ++mt)
      #pragma unroll
      for (int nt = 0; nt < 4; ++nt) acc[mt][nt] = (f32x4){0.f,0.f,0.f,0.f};
    for (int w8 = 0; w8 < 8; ++w8) {
      __syncthreads();
      for (int i = tid; i < 64 * 16; i += 192) {
        int row = i >> 4, c8 = i & 15;
        *((uint4*)&Bw[row * 136 + c8 * 8]) = ((const uint4*)c1wT)[(w8 * 64 + row) * 16 + c8];
      }
      __syncthreads();
      #pragma unroll
      for (int ks = 0; ks < 4; ++ks) {
        int kof = ks * 32 + q * 8;
        short8 a[3], bb[4];
        #pragma unroll
        for (int mt = 0; mt < 3; ++mt) {
          int tl = wv + 3 * mt;
          a[mt] = *(const short8*)&At[(tl * 16 + m + w8) * 136 + kof];
        }
        #pragma unroll
        for (int nt = 0; nt < 4; ++nt)
          bb[nt] = *(const short8*)&Bw[(nt * 16 + m) * 136 + kof];
        #pragma unroll
        for (int mt = 0; mt < 3; ++mt)
          #pragma unroll
          for (int nt = 0; nt < 4; ++nt)
            acc[mt][nt] = __builtin_amdgcn_mfma_f32_16x16x32_bf16(a[mt], bb[nt], acc[mt][nt], 0, 0, 0);
      }
    }
    #pragma unroll
    for (int mt = 0; mt < 3; ++mt) {
      int tl = wv + 3 * mt;
      #pragma unroll
      for (int nt = 0; nt < 4; ++nt) {
        int c = nt * 16 + m;
        float bs = c1b[c];
        #pragma unroll
        for (int r = 0; r < 4; ++r) {
          float v = fmaxf(acc[mt][nt][r] + bs, 0.f);
          l1buf[(tl * 16 + q * 4 + r) * 72 + c] = f2bf(v);
        }
      }
    }
    __syncthreads();
    for (int i2 = tid; i2 < 135 * 8; i2 += 192) {
      int i = i2 >> 3, c8 = i2 & 7;
      int jrow = l0 - 3 + i;
      if (jrow < 0 || jrow > 2047) {
        uint4 z4 = {0u,0u,0u,0u};
        *((uint4*)&l1buf[i * 72 + c8 * 8]) = z4;
      }
    }
    // ---- conv2: out rows [l0, l0+127] (8 M-tiles), K=64 ----
    f32x4 acc2[3][4];
    #pragma unroll
    for (int mt = 0; mt < 3; ++mt)
      #pragma unroll
      for (int nt = 0; nt < 4; ++nt) acc2[mt][nt] = (f32x4){0.f,0.f,0.f,0.f};
    for (int w8 = 0; w8 < 8; ++w8) {
      __syncthreads();
      for (int i = tid; i < 64 * 8; i += 192) {
        int row = i >> 3, c8 = i & 7;
        *((uint4*)&Bw[row * 72 + c8 * 8]) = ((const uint4*)c2wT)[(w8 * 64 + row) * 8 + c8];
      }
      __syncthreads();
      #pragma unroll
      for (int ks = 0; ks < 2; ++ks) {
        int kof = ks * 32 + q * 8;
        short8 a[3], bb[4];
        #pragma unroll
        for (int mt = 0; mt < 3; ++mt) {
          int tl = wv + 3 * mt;
          if (tl < 8)
            a[mt] = *(const short8*)&l1buf[(tl * 16 + m + w8) * 72 + kof];
        }
        #pragma unroll
        for (int nt = 0; nt < 4; ++nt)
          bb[nt] = *(const short8*)&Bw[(nt * 16 + m) * 72 + kof];
        #pragma unroll
        for (int mt = 0; mt < 3; ++mt) {
          int tl = wv + 3 * mt;
          if (tl < 8)
            #pragma unroll
            for (int nt = 0; nt < 4; ++nt)
              acc2[mt][nt] = __builtin_amdgcn_mfma_f32_16x16x32_bf16(a[mt], bb[nt], acc2[mt][nt], 0, 0, 0);
        }
      }
    }
    #pragma unroll
    for (int mt = 0; mt < 3; ++mt) {
      int tl = wv + 3 * mt;
      if (tl < 8) {
        #pragma unroll
        for (int nt = 0; nt < 4; ++nt) {
          int c = nt * 16 + m;
          float bs = c2b[c];
          #pragma unroll
          for (int r = 0; r < 4; ++r)
            c2o[(size_t)(b * L_ + l0 + tl * 16 + q * 4 + r) * 64 + c] = f2bf(acc2[mt][nt][r] + bs);
        }
      }
    }
  }
}

// ---------------------------------------------------------------------------
// K5: per-batch tail: L2=c2o*h_t -> l2norm -> conv3 -> softmax alpha ->
//     n_hat = sum alpha*tok -> logits = tok.n_hat + bias -> softmax -> out
// ---------------------------------------------------------------------------
__global__ __launch_bounds__(256) void k_final(
    const unsigned short* __restrict__ tokpad, const unsigned short* __restrict__ c2o,
    const float* __restrict__ h_t, const float* __restrict__ c3w,
    const float* __restrict__ c3b, const float* __restrict__ biasg,
    float* __restrict__ out)
{
  __shared__ float Lf[71 * 65];
  __shared__ float a_lds[2048];
  __shared__ float l_lds[2048];
  __shared__ float red[256];
  __shared__ float nred[512];
  __shared__ float nhat[128];
  __shared__ float ht[64];
  __shared__ float c3[512];
  int b = blockIdx.x, tid = threadIdx.x, lane = tid & 63, wave = tid >> 6;
  if (tid < 64) ht[tid] = h_t[b * 64 + tid];
  for (int i = tid; i < 512; i += 256) c3[i] = c3w[i];
  float c3bias = c3b[0];
  __syncthreads();
  // ---- pass 1: a_logits via normalized features + conv3 (tiles of 64 l) ----
  for (int tile = 0; tile < 32; ++tile) {
    int lt = tile << 6;
    for (int i0 = wave; i0 < 71; i0 += 4) {
      int l = lt - 3 + i0;
      float v = 0.f;
      if (l >= 0 && l < L_) v = bf2f(c2o[((size_t)b * L_ + l) * 64 + lane]) * ht[lane];
      float ss = v * v;
      #pragma unroll
      for (int msk = 1; msk < 64; msk <<= 1) ss += __shfl_xor(ss, msk);
      Lf[i0 * 65 + lane] = v * rsqrtf(ss + 1e-12f);
    }
    __syncthreads();
    {
      int u = lane, part = wave;
      float p = 0.f;
      #pragma unroll
      for (int w = 0; w < 8; ++w)
        #pragma unroll
        for (int cc = 0; cc < 16; ++cc) {
          int c = part * 16 + cc;
          p += Lf[(u + w) * 65 + c] * c3[w * 64 + c];
        }
      red[tid] = p;
    }
    __syncthreads();
    if (tid < 64) a_lds[lt + tid] = red[tid] + red[64 + tid] + red[128 + tid] + red[192 + tid] + c3bias;
    __syncthreads();
  }
  // ---- pass 2: softmax alpha over 2048 ----
  {
    float mx = -1e30f;
    for (int i = tid; i < 2048; i += 256) mx = fmaxf(mx, a_lds[i]);
    #pragma unroll
    for (int msk = 1; msk < 64; msk <<= 1) mx = fmaxf(mx, __shfl_xor(mx, msk));
    if (lane == 0) red[wave] = mx;
    __syncthreads();
    mx = fmaxf(fmaxf(red[0], red[1]), fmaxf(red[2], red[3]));
    float sm = 0.f;
    for (int i = tid; i < 2048; i += 256) sm += __expf(a_lds[i] - mx);
    #pragma unroll
    for (int msk = 1; msk < 64; msk <<= 1) sm += __shfl_xor(sm, msk);
    __syncthreads();
    if (lane == 0) red[wave] = sm;
    __syncthreads();
    sm = red[0] + red[1] + red[2] + red[3];
    float inv = 1.f / sm;
    for (int i = tid; i < 2048; i += 256) a_lds[i] = __expf(a_lds[i] - mx) * inv;
    __syncthreads();
  }
  // ---- pass 3: n_hat[128] = sum_l alpha_l * tok[l][:] ----
  {
    int d2 = tid & 63, g = tid >> 6;
    float ax = 0.f, ay = 0.f;
    for (int l = g; l < L_; l += 4) {
      unsigned int uu = *(const unsigned int*)&tokpad[((size_t)b * LP + PAD + l) * 128 + d2 * 2];
      float al = a_lds[l];
      ax += al * bf2f((unsigned short)(uu & 0xffffu));
      ay += al * bf2f((unsigned short)(uu >> 16));
    }
    nred[g * 128 + d2 * 2] = ax;
    nred[g * 128 + d2 * 2 + 1] = ay;
    __syncthreads();
    if (tid < 128) nhat[tid] = nred[tid] + nred[128 + tid] + nred[256 + tid] + nred[384 + tid];
    __syncthreads();
  }
  // ---- pass 4: logits = tok . n_hat + bias ----
  for (int li = 0; li < 8; ++li) {
    int l = li * 256 + tid;
    const uint4* rowp = (const uint4*)&tokpad[((size_t)b * LP + PAD + l) * 128];
    float s = 0.f;
    #pragma unroll
    for (int jj = 0; jj < 16; ++jj) {
      uint4 uu = rowp[jj];
      s += bf2f((unsigned short)(uu.x & 0xffffu)) * nhat[jj*8+0]
         + bf2f((unsigned short)(uu.x >> 16))     * nhat[jj*8+1]
         + bf2f((unsigned short)(uu.y & 0xffffu)) * nhat[jj*8+2]
         + bf2f((unsigned short)(uu.y >> 16))     * nhat[jj*8+3]
         + bf2f((unsigned short)(uu.z & 0xffffu)) * nhat[jj*8+4]
         + bf2f((unsigned short)(uu.z >> 16))     * nhat[jj*8+5]
         + bf2f((unsigned short)(uu.w & 0xffffu)) * nhat[jj*8+6]
         + bf2f((unsigned short)(uu.w >> 16))     * nhat[jj*8+7];
    }
    l_lds[l] = s + biasg[b * L_ + l];
  }
  __syncthreads();
  // ---- pass 5: final softmax -> out ----
  {
    float mx = -1e30f;
    for (int i = tid; i < 2048; i += 256) mx = fmaxf(mx, l_lds[i]);
    #pragma unroll
    for (int msk = 1; msk < 64; msk <<= 1) mx = fmaxf(mx, __shfl_xor(mx, msk));
    __syncthreads();
    if (lane == 0) red[wave] = mx;
    __syncthreads();
    mx = fmaxf(fmaxf(red[0], red[1]), fmaxf(red[2], red[3]));
    float sm = 0.f;
    for (int i = tid; i < 2048; i += 256) sm += __expf(l_lds[i] - mx);
    #pragma unroll
    for (int msk = 1; msk < 64; msk <<= 1) sm += __shfl_xor(sm, msk);
    __syncthreads();
    if (lane == 0) red[wave] = sm;
    __syncthreads();
    sm = red[0] + red[1] + red[2] + red[3];
    float inv = 1.f / sm;
    for (int i = tid; i < 2048; i += 256) out[b * L_ + i] = __expf(l_lds[i] - mx) * inv;
  }
}

// ---------------------------------------------------------------------------
extern "C" void kernel_launch(void* const* d_in, const int* in_sizes, int n_in,
                              void* d_out, int out_size, void* d_ws, size_t ws_size,
                              hipStream_t stream) {
  const int*   code = (const int*)d_in[0];
  const float* E    = (const float*)d_in[1];
  const float* bt   = (const float*)d_in[2];
  const float* Wx   = (const float*)d_in[3];
  const float* Wh   = (const float*)d_in[4];
  const float* bg   = (const float*)d_in[5];
  const float* c1w  = (const float*)d_in[6];
  const float* c1b  = (const float*)d_in[7];
  const float* c2w  = (const float*)d_in[8];
  const float* c2b  = (const float*)d_in[9];
  const float* c3w  = (const float*)d_in[10];
  const float* c3b  = (const float*)d_in[11];
  char* ws = (char*)d_ws;
  unsigned short* tokpad = (unsigned short*)(ws);               // 33,685,504 B
  unsigned short* xg     = (unsigned short*)(ws + 33685504);    // 67,108,864 B
  unsigned short* c2o    = (unsigned short*)(ws + 100794368);   // 16,777,216 B
  unsigned short* WxT    = (unsigned short*)(ws + 117571584);   //     49,152 B
  unsigned short* c1wT   = (unsigned short*)(ws + 117620736);   //    131,072 B
  unsigned short* c2wT   = (unsigned short*)(ws + 117751808);   //     65,536 B
  float*          htp    = (float*)(ws + 117817344);            //     16,384 B
  float*          biasg  = (float*)(ws + 117833728);            //    524,288 B
  // total ws use: 118,358,016 B

  k_prep <<<9216, 256, 0, stream>>>(code, E, bt, Wx, c1w, c2w, tokpad, WxT, c1wT, c2wT, biasg);
  k_xproj<<<1024, 256, 0, stream>>>(tokpad, WxT, bg, xg);
  k_fused<<<256, 192, 0, stream>>>(xg, Wh, bg, htp, tokpad, c1wT, c1b, c2wT, c2b, c2o);
  k_final<<<64, 256, 0, stream>>>(tokpad, c2o, htp, c3w, c3b, biasg, (float*)d_out);
}